// Round 1
// baseline (1518.961 us; speedup 1.0000x reference)
//
#include <hip/hip_runtime.h>
#include <stdint.h>

#define N_NODES 100000
#define N_EDGES 1600000
#define DIM 128
#define NLAYERS 4
#define NGRAPH 128
#define NCLS 10
#define EPSV 1e-5f

#define SCAN_B 512
#define SCAN_NB ((N_NODES + SCAN_B - 1) / SCAN_B)   // 196
#define NCHUNK 16
#define GEMM_ROWS 32

// ---------------- prepass kernels ----------------

__global__ void k_init(int* __restrict__ deg, int* __restrict__ cursor, int* __restrict__ cntg) {
    int i = blockIdx.x * blockDim.x + threadIdx.x;
    if (i < N_NODES) { deg[i] = 1; cursor[i] = 0; }
    if (i < NGRAPH) cntg[i] = 0;
}

__global__ void k_edge_deg(const int* __restrict__ ei, int* __restrict__ deg) {
    int e = blockIdx.x * blockDim.x + threadIdx.x;
    if (e < N_EDGES) atomicAdd(&deg[ei[N_EDGES + e]], 1);
}

__global__ void k_node_dis(const int* __restrict__ deg, float* __restrict__ dis,
                           const int* __restrict__ batch, int* __restrict__ cntg) {
    int i = blockIdx.x * blockDim.x + threadIdx.x;
    if (i < N_NODES) {
        dis[i] = rsqrtf((float)deg[i]);
        atomicAdd(&cntg[batch[i]], 1);
    }
}

__global__ __launch_bounds__(SCAN_B) void k_scan_bsum(const int* __restrict__ deg, int* __restrict__ bsum) {
    __shared__ int s[SCAN_B];
    int t = threadIdx.x;
    int n = blockIdx.x * SCAN_B + t;
    int v = (n < N_NODES) ? deg[n] - 1 : 0;
    s[t] = v; __syncthreads();
    for (int off = SCAN_B / 2; off > 0; off >>= 1) {
        if (t < off) s[t] += s[t + off];
        __syncthreads();
    }
    if (t == 0) bsum[blockIdx.x] = s[0];
}

__global__ __launch_bounds__(256) void k_scan_mid(const int* __restrict__ bsum, int* __restrict__ boff,
                                                  const int* __restrict__ cntg, int* __restrict__ gstart,
                                                  float* __restrict__ cntf) {
    __shared__ int s[256];
    int t = threadIdx.x;
    // scan block sums (exclusive)
    int v = (t < SCAN_NB) ? bsum[t] : 0;
    s[t] = v; __syncthreads();
    for (int off = 1; off < 256; off <<= 1) {
        int a = (t >= off) ? s[t - off] : 0;
        __syncthreads();
        s[t] += a;
        __syncthreads();
    }
    if (t < SCAN_NB) boff[t] = s[t] - v;
    __syncthreads();
    // scan graph counts (exclusive) -> gstart
    int c = (t < NGRAPH) ? cntg[t] : 0;
    s[t] = c; __syncthreads();
    for (int off = 1; off < 256; off <<= 1) {
        int a = (t >= off) ? s[t - off] : 0;
        __syncthreads();
        s[t] += a;
        __syncthreads();
    }
    if (t < NGRAPH) { gstart[t] = s[t] - c; cntf[t] = (float)c; }
    if (t == 0) gstart[NGRAPH] = N_NODES;
}

__global__ __launch_bounds__(SCAN_B) void k_scan_final(const int* __restrict__ deg, const int* __restrict__ boff,
                                                       int* __restrict__ rowoff) {
    __shared__ int s[SCAN_B];
    int t = threadIdx.x;
    int n = blockIdx.x * SCAN_B + t;
    int v = (n < N_NODES) ? deg[n] - 1 : 0;
    s[t] = v; __syncthreads();
    for (int off = 1; off < SCAN_B; off <<= 1) {
        int a = (t >= off) ? s[t - off] : 0;
        __syncthreads();
        s[t] += a;
        __syncthreads();
    }
    int excl = s[t] - v;
    if (n <= N_NODES) rowoff[n] = boff[blockIdx.x] + excl;
}

__global__ void k_build_csc(const int* __restrict__ ei, const float* __restrict__ dis,
                            const int* __restrict__ rowoff, int* __restrict__ cursor,
                            int* __restrict__ csc_src, float* __restrict__ csc_w) {
    int e = blockIdx.x * blockDim.x + threadIdx.x;
    if (e >= N_EDGES) return;
    int s = ei[e];
    int d = ei[N_EDGES + e];
    int pos = rowoff[d] + atomicAdd(&cursor[d], 1);
    csc_src[pos] = s;
    csc_w[pos] = dis[s] * dis[d];
}

// ---------------- per-layer kernels ----------------

// H[N,128] = X[N,128] @ W[128,128], fp32, 32 rows per block, 256 threads, 4x4 per thread
__global__ __launch_bounds__(256) void k_gemm(const float* __restrict__ X, const float* __restrict__ W,
                                              float* __restrict__ H) {
    __shared__ float sX[GEMM_ROWS][DIM];
    __shared__ float sW[64][DIM];
    int t = threadIdx.x;
    size_t row0 = (size_t)blockIdx.x * GEMM_ROWS;

    const float4* Xv = (const float4*)(X + row0 * DIM);
    float4* sXv = (float4*)&sX[0][0];
#pragma unroll
    for (int i = 0; i < 4; i++) sXv[t + 256 * i] = Xv[t + 256 * i];

    float4 acc[4];
#pragma unroll
    for (int r = 0; r < 4; r++) acc[r] = make_float4(0.f, 0.f, 0.f, 0.f);

    int tc = (t & 31) * 4;
    int tr = (t >> 5) * 4;

    for (int kb = 0; kb < 2; ++kb) {
        __syncthreads();
        const float4* Wv = (const float4*)(W + (size_t)kb * 64 * DIM);
        float4* sWv = (float4*)&sW[0][0];
#pragma unroll
        for (int i = 0; i < 8; i++) sWv[t + 256 * i] = Wv[t + 256 * i];
        __syncthreads();
#pragma unroll 4
        for (int k = 0; k < 64; k += 4) {
            float4 xr[4];
#pragma unroll
            for (int r = 0; r < 4; r++) xr[r] = *(const float4*)&sX[tr + r][kb * 64 + k];
#pragma unroll
            for (int j = 0; j < 4; j++) {
                float4 wv = *(const float4*)&sW[k + j][tc];
#pragma unroll
                for (int r = 0; r < 4; r++) {
                    float xv = (j == 0) ? xr[r].x : (j == 1) ? xr[r].y : (j == 2) ? xr[r].z : xr[r].w;
                    acc[r].x += xv * wv.x;
                    acc[r].y += xv * wv.y;
                    acc[r].z += xv * wv.z;
                    acc[r].w += xv * wv.w;
                }
            }
        }
    }
    float* Hb = H + row0 * DIM;
#pragma unroll
    for (int r = 0; r < 4; r++) *(float4*)&Hb[(tr + r) * DIM + tc] = acc[r];
}

// pull-based aggregation: one block (128 threads) per dst node
__global__ __launch_bounds__(128) void k_aggregate(const float* __restrict__ H, const int* __restrict__ csc_src,
                                                   const float* __restrict__ csc_w, const int* __restrict__ rowoff,
                                                   const float* __restrict__ dis, const float* __restrict__ bias,
                                                   float* __restrict__ Out) {
    int n = blockIdx.x;
    int f = threadIdx.x;
    float self = dis[n];
    float acc = self * self * H[(size_t)n * DIM + f];
    int b0 = rowoff[n], b1 = rowoff[n + 1];
    int j = b0;
    for (; j + 1 < b1; j += 2) {
        int s0 = csc_src[j];
        int s1 = csc_src[j + 1];
        float w0 = csc_w[j];
        float w1 = csc_w[j + 1];
        float v0 = H[(size_t)s0 * DIM + f];
        float v1 = H[(size_t)s1 * DIM + f];
        acc += w0 * v0;
        acc += w1 * v1;
    }
    if (j < b1) {
        int s0 = csc_src[j];
        acc += csc_w[j] * H[(size_t)s0 * DIM + f];
    }
    Out[(size_t)n * DIM + f] = acc + bias[f];
}

__global__ void k_zero(float* __restrict__ p, int n) {
    int i = blockIdx.x * blockDim.x + threadIdx.x;
    if (i < n) p[i] = 0.f;
}

__global__ __launch_bounds__(128) void k_stats_partial(const float* __restrict__ A, const int* __restrict__ gstart,
                                                       float* __restrict__ gsum, float* __restrict__ gsumsq) {
    int g = blockIdx.x / NCHUNK;
    int c = blockIdx.x % NCHUNK;
    int s0 = gstart[g], s1 = gstart[g + 1];
    int len = s1 - s0;
    int a = s0 + (int)((long)len * c / NCHUNK);
    int b = s0 + (int)((long)len * (c + 1) / NCHUNK);
    int f = threadIdx.x;
    float s = 0.f, s2 = 0.f;
    for (int n = a; n < b; ++n) {
        float v = A[(size_t)n * DIM + f];
        s += v;
        s2 += v * v;
    }
    if (b > a) {
        atomicAdd(&gsum[g * DIM + f], s);
        atomicAdd(&gsumsq[g * DIM + f], s2);
    }
}

__global__ void k_stats_final(const float* __restrict__ gsum, const float* __restrict__ gsumsq,
                              const float* __restrict__ cntf, const float* __restrict__ mscale,
                              float* __restrict__ amean, float* __restrict__ rstd) {
    int i = blockIdx.x * blockDim.x + threadIdx.x;
    if (i >= NGRAPH * DIM) return;
    int g = i / DIM, f = i % DIM;
    float cnt = cntf[g];
    float inv = (cnt > 0.f) ? 1.0f / cnt : 0.f;
    float m = gsum[i] * inv;
    float a = mscale[f];
    float var = gsumsq[i] * inv - (2.f * a - a * a) * m * m;
    amean[i] = a * m;
    rstd[i] = rsqrtf(var + EPSV);
}

__global__ void k_norm(const float* __restrict__ A, const int* __restrict__ batch,
                       const float* __restrict__ amean, const float* __restrict__ rstd,
                       const float* __restrict__ gw, const float* __restrict__ gb,
                       const float* __restrict__ res, float* __restrict__ xout) {
    int i = blockIdx.x * blockDim.x + threadIdx.x;  // over N*32 float4 groups
    if (i >= N_NODES * 32) return;
    int n = i >> 5, q = i & 31;
    int g = batch[n];
    float4 v = ((const float4*)A)[i];
    float4 am = ((const float4*)amean)[g * 32 + q];
    float4 rs = ((const float4*)rstd)[g * 32 + q];
    float4 w = ((const float4*)gw)[q];
    float4 b = ((const float4*)gb)[q];
    float4 r = ((const float4*)res)[i];
    float4 o;
    o.x = w.x * (v.x - am.x) * rs.x + b.x;
    o.y = w.y * (v.y - am.y) * rs.y + b.y;
    o.z = w.z * (v.z - am.z) * rs.z + b.z;
    o.w = w.w * (v.w - am.w) * rs.w + b.w;
    o.x = ((o.x > 0.f) ? o.x : expm1f(o.x)) + r.x;
    o.y = ((o.y > 0.f) ? o.y : expm1f(o.y)) + r.y;
    o.z = ((o.z > 0.f) ? o.z : expm1f(o.z)) + r.z;
    o.w = ((o.w > 0.f) ? o.w : expm1f(o.w)) + r.w;
    ((float4*)xout)[i] = o;
}

__global__ __launch_bounds__(128) void k_pool_partial(const float* __restrict__ X, const int* __restrict__ gstart,
                                                      float* __restrict__ pooled) {
    int g = blockIdx.x / NCHUNK;
    int c = blockIdx.x % NCHUNK;
    int s0 = gstart[g], s1 = gstart[g + 1];
    int len = s1 - s0;
    int a = s0 + (int)((long)len * c / NCHUNK);
    int b = s0 + (int)((long)len * (c + 1) / NCHUNK);
    int f = threadIdx.x;
    float s = 0.f;
    for (int n = a; n < b; ++n) s += X[(size_t)n * DIM + f];
    if (b > a) atomicAdd(&pooled[g * DIM + f], s);
}

__global__ __launch_bounds__(128) void k_head(const float* __restrict__ pooled,
                                              const float* __restrict__ w1, const float* __restrict__ b1,
                                              const float* __restrict__ gamma, const float* __restrict__ beta,
                                              const float* __restrict__ rmean, const float* __restrict__ rvar,
                                              const float* __restrict__ w2, const float* __restrict__ b2,
                                              float* __restrict__ zout) {
    __shared__ float sp[DIM];
    __shared__ float sz[DIM];
    int g = blockIdx.x, t = threadIdx.x;
    sp[t] = pooled[g * DIM + t];
    __syncthreads();
    float acc = b1[t];
#pragma unroll 8
    for (int k = 0; k < DIM; k++) acc += sp[k] * w1[k * DIM + t];
    acc = gamma[t] * (acc - rmean[t]) * rsqrtf(rvar[t] + EPSV) + beta[t];
    acc = fmaxf(acc, 0.f);
    sz[t] = acc;
    __syncthreads();
    if (t < NCLS) {
        float a2 = b2[t];
#pragma unroll 8
        for (int k = 0; k < DIM; k++) a2 += sz[k] * w2[k * NCLS + t];
        zout[g * NCLS + t] = a2;
    }
}

// ---------------- launch ----------------

extern "C" void kernel_launch(void* const* d_in, const int* in_sizes, int n_in,
                              void* d_out, int out_size, void* d_ws, size_t ws_size,
                              hipStream_t stream) {
    const float* x_in   = (const float*)d_in[0];
    const int*   ei     = (const int*)d_in[1];
    const int*   batch  = (const int*)d_in[2];
    const float* conv_w = (const float*)d_in[3];
    const float* conv_b = (const float*)d_in[4];
    const float* gn_w   = (const float*)d_in[5];
    const float* gn_b   = (const float*)d_in[6];
    const float* gn_ms  = (const float*)d_in[7];
    const float* w1     = (const float*)d_in[8];
    const float* b1     = (const float*)d_in[9];
    const float* bng    = (const float*)d_in[10];
    const float* bnb    = (const float*)d_in[11];
    const float* bnm    = (const float*)d_in[12];
    const float* bnv    = (const float*)d_in[13];
    const float* w2     = (const float*)d_in[14];
    const float* b2     = (const float*)d_in[15];

    float* out_x = (float*)d_out;
    float* out_z = out_x + (size_t)N_NODES * DIM;

    char* ws = (char*)d_ws;
    size_t off = 0;
    auto alloc = [&](size_t bytes) -> void* {
        void* p = ws + off;
        off += (bytes + 255) / 256 * 256;
        return p;
    };
    float* h       = (float*)alloc(sizeof(float) * (size_t)N_NODES * DIM);
    float* agg     = (float*)alloc(sizeof(float) * (size_t)N_NODES * DIM);
    int*   csc_src = (int*)alloc(sizeof(int) * (size_t)N_EDGES);
    float* csc_w   = (float*)alloc(sizeof(float) * (size_t)N_EDGES);
    int*   deg     = (int*)alloc(sizeof(int) * N_NODES);
    float* dis     = (float*)alloc(sizeof(float) * N_NODES);
    int*   cursor  = (int*)alloc(sizeof(int) * N_NODES);
    int*   rowoff  = (int*)alloc(sizeof(int) * (N_NODES + 1));
    int*   bsum    = (int*)alloc(sizeof(int) * SCAN_NB);
    int*   boff    = (int*)alloc(sizeof(int) * SCAN_NB);
    int*   cntg    = (int*)alloc(sizeof(int) * NGRAPH);
    float* cntf    = (float*)alloc(sizeof(float) * NGRAPH);
    int*   gstart  = (int*)alloc(sizeof(int) * (NGRAPH + 1));
    float* gsum    = (float*)alloc(sizeof(float) * 2 * NGRAPH * DIM);  // gsum | gsumsq contiguous
    float* gsumsq  = gsum + NGRAPH * DIM;
    float* amean   = (float*)alloc(sizeof(float) * NGRAPH * DIM);
    float* rstd    = (float*)alloc(sizeof(float) * NGRAPH * DIM);
    float* pooled  = (float*)alloc(sizeof(float) * NGRAPH * DIM);

    // ---- prepass: degrees, graph offsets, CSC build ----
    k_init<<<(N_NODES + 255) / 256, 256, 0, stream>>>(deg, cursor, cntg);
    k_edge_deg<<<(N_EDGES + 255) / 256, 256, 0, stream>>>(ei, deg);
    k_node_dis<<<(N_NODES + 255) / 256, 256, 0, stream>>>(deg, dis, batch, cntg);
    k_scan_bsum<<<SCAN_NB, SCAN_B, 0, stream>>>(deg, bsum);
    k_scan_mid<<<1, 256, 0, stream>>>(bsum, boff, cntg, gstart, cntf);
    k_scan_final<<<SCAN_NB, SCAN_B, 0, stream>>>(deg, boff, rowoff);
    k_build_csc<<<(N_EDGES + 255) / 256, 256, 0, stream>>>(ei, dis, rowoff, cursor, csc_src, csc_w);

    // ---- layers ----
    const float* xcur = x_in;
    for (int l = 0; l < NLAYERS; l++) {
        k_gemm<<<N_NODES / GEMM_ROWS, 256, 0, stream>>>(xcur, conv_w + (size_t)l * DIM * DIM, h);
        k_aggregate<<<N_NODES, 128, 0, stream>>>(h, csc_src, csc_w, rowoff, dis, conv_b + (size_t)l * DIM, agg);
        k_zero<<<(2 * NGRAPH * DIM + 255) / 256, 256, 0, stream>>>(gsum, 2 * NGRAPH * DIM);
        k_stats_partial<<<NGRAPH * NCHUNK, 128, 0, stream>>>(agg, gstart, gsum, gsumsq);
        k_stats_final<<<(NGRAPH * DIM + 255) / 256, 256, 0, stream>>>(gsum, gsumsq, cntf, gn_ms + (size_t)l * DIM,
                                                                      amean, rstd);
        k_norm<<<(N_NODES * 32 + 255) / 256, 256, 0, stream>>>(agg, batch, amean, rstd, gn_w + (size_t)l * DIM,
                                                               gn_b + (size_t)l * DIM, xcur, out_x);
        xcur = out_x;
    }

    // ---- pool + head ----
    k_zero<<<(NGRAPH * DIM + 255) / 256, 256, 0, stream>>>(pooled, NGRAPH * DIM);
    k_pool_partial<<<NGRAPH * NCHUNK, 128, 0, stream>>>(out_x, gstart, pooled);
    k_head<<<NGRAPH, DIM, 0, stream>>>(pooled, w1, b1, bng, bnb, bnm, bnv, w2, b2, out_z);
}

// Round 2
// 1250.992 us; speedup vs baseline: 1.2142x; 1.2142x over previous
//
#include <hip/hip_runtime.h>
#include <stdint.h>

#define N_NODES 100000
#define N_EDGES 1600000
#define DIM 128
#define NLAYERS 4
#define NGRAPH 128
#define NCLS 10
#define EPSV 1e-5f

#define SCAN_B 512
#define SCAN_NB ((N_NODES + SCAN_B - 1) / SCAN_B)   // 196
#define NCHUNK 16
#define GEMM_ROWS 32

// ---------------- prepass kernels ----------------

__global__ void k_init(int* __restrict__ deg, int* __restrict__ cursor) {
    int i = blockIdx.x * blockDim.x + threadIdx.x;
    if (i < N_NODES) { deg[i] = 1; cursor[i] = 0; }
}

__global__ void k_edge_deg(const int* __restrict__ ei, int* __restrict__ deg) {
    int e = blockIdx.x * blockDim.x + threadIdx.x;
    if (e < N_EDGES) atomicAdd(&deg[ei[N_EDGES + e]], 1);
}

__global__ void k_node_dis(const int* __restrict__ deg, float* __restrict__ dis) {
    int i = blockIdx.x * blockDim.x + threadIdx.x;
    if (i < N_NODES) dis[i] = rsqrtf((float)deg[i]);
}

// graph segment boundaries from the SORTED batch array — no atomics
__global__ void k_gbound(const int* __restrict__ batch, int* __restrict__ gstart) {
    int i = blockIdx.x * blockDim.x + threadIdx.x;
    if (i >= N_NODES) return;
    int b = batch[i];
    if (i == 0) {
        for (int g = 0; g <= b; g++) gstart[g] = 0;
    } else {
        int bp = batch[i - 1];
        for (int g = bp + 1; g <= b; g++) gstart[g] = i;
    }
    if (i == N_NODES - 1) {
        for (int g = b + 1; g <= NGRAPH; g++) gstart[g] = N_NODES;
    }
}

__global__ __launch_bounds__(SCAN_B) void k_scan_bsum(const int* __restrict__ deg, int* __restrict__ bsum) {
    __shared__ int s[SCAN_B];
    int t = threadIdx.x;
    int n = blockIdx.x * SCAN_B + t;
    int v = (n < N_NODES) ? deg[n] - 1 : 0;
    s[t] = v; __syncthreads();
    for (int off = SCAN_B / 2; off > 0; off >>= 1) {
        if (t < off) s[t] += s[t + off];
        __syncthreads();
    }
    if (t == 0) bsum[blockIdx.x] = s[0];
}

__global__ __launch_bounds__(256) void k_scan_mid(const int* __restrict__ bsum, int* __restrict__ boff,
                                                  const int* __restrict__ gstart, float* __restrict__ cntf) {
    __shared__ int s[256];
    int t = threadIdx.x;
    // scan block sums (exclusive)
    int v = (t < SCAN_NB) ? bsum[t] : 0;
    s[t] = v; __syncthreads();
    for (int off = 1; off < 256; off <<= 1) {
        int a = (t >= off) ? s[t - off] : 0;
        __syncthreads();
        s[t] += a;
        __syncthreads();
    }
    if (t < SCAN_NB) boff[t] = s[t] - v;
    // per-graph node counts from boundaries
    if (t < NGRAPH) cntf[t] = (float)(gstart[t + 1] - gstart[t]);
}

__global__ __launch_bounds__(SCAN_B) void k_scan_final(const int* __restrict__ deg, const int* __restrict__ boff,
                                                       int* __restrict__ rowoff) {
    __shared__ int s[SCAN_B];
    int t = threadIdx.x;
    int n = blockIdx.x * SCAN_B + t;
    int v = (n < N_NODES) ? deg[n] - 1 : 0;
    s[t] = v; __syncthreads();
    for (int off = 1; off < SCAN_B; off <<= 1) {
        int a = (t >= off) ? s[t - off] : 0;
        __syncthreads();
        s[t] += a;
        __syncthreads();
    }
    int excl = s[t] - v;
    if (n <= N_NODES) rowoff[n] = boff[blockIdx.x] + excl;
}

__global__ void k_build_csc(const int* __restrict__ ei, const float* __restrict__ dis,
                            const int* __restrict__ rowoff, int* __restrict__ cursor,
                            int* __restrict__ csc_src, float* __restrict__ csc_w) {
    int e = blockIdx.x * blockDim.x + threadIdx.x;
    if (e >= N_EDGES) return;
    int s = ei[e];
    int d = ei[N_EDGES + e];
    int pos = rowoff[d] + atomicAdd(&cursor[d], 1);
    csc_src[pos] = s;
    csc_w[pos] = dis[s] * dis[d];
}

// ---------------- per-layer kernels ----------------

// H[N,128] = X[N,128] @ W[128,128], fp32, 32 rows per block, 256 threads, 4x4 per thread
__global__ __launch_bounds__(256) void k_gemm(const float* __restrict__ X, const float* __restrict__ W,
                                              float* __restrict__ H) {
    __shared__ float sX[GEMM_ROWS][DIM];
    __shared__ float sW[64][DIM];
    int t = threadIdx.x;
    size_t row0 = (size_t)blockIdx.x * GEMM_ROWS;

    const float4* Xv = (const float4*)(X + row0 * DIM);
    float4* sXv = (float4*)&sX[0][0];
#pragma unroll
    for (int i = 0; i < 4; i++) sXv[t + 256 * i] = Xv[t + 256 * i];

    float4 acc[4];
#pragma unroll
    for (int r = 0; r < 4; r++) acc[r] = make_float4(0.f, 0.f, 0.f, 0.f);

    int tc = (t & 31) * 4;
    int tr = (t >> 5) * 4;

    for (int kb = 0; kb < 2; ++kb) {
        __syncthreads();
        const float4* Wv = (const float4*)(W + (size_t)kb * 64 * DIM);
        float4* sWv = (float4*)&sW[0][0];
#pragma unroll
        for (int i = 0; i < 8; i++) sWv[t + 256 * i] = Wv[t + 256 * i];
        __syncthreads();
#pragma unroll 4
        for (int k = 0; k < 64; k += 4) {
            float4 xr[4];
#pragma unroll
            for (int r = 0; r < 4; r++) xr[r] = *(const float4*)&sX[tr + r][kb * 64 + k];
#pragma unroll
            for (int j = 0; j < 4; j++) {
                float4 wv = *(const float4*)&sW[k + j][tc];
#pragma unroll
                for (int r = 0; r < 4; r++) {
                    float xv = (j == 0) ? xr[r].x : (j == 1) ? xr[r].y : (j == 2) ? xr[r].z : xr[r].w;
                    acc[r].x += xv * wv.x;
                    acc[r].y += xv * wv.y;
                    acc[r].z += xv * wv.z;
                    acc[r].w += xv * wv.w;
                }
            }
        }
    }
    float* Hb = H + row0 * DIM;
#pragma unroll
    for (int r = 0; r < 4; r++) *(float4*)&Hb[(tr + r) * DIM + tc] = acc[r];
}

// pull-based aggregation: one block (128 threads) per dst node
__global__ __launch_bounds__(128) void k_aggregate(const float* __restrict__ H, const int* __restrict__ csc_src,
                                                   const float* __restrict__ csc_w, const int* __restrict__ rowoff,
                                                   const float* __restrict__ dis, const float* __restrict__ bias,
                                                   float* __restrict__ Out) {
    int n = blockIdx.x;
    int f = threadIdx.x;
    float self = dis[n];
    float acc = self * self * H[(size_t)n * DIM + f];
    int b0 = rowoff[n], b1 = rowoff[n + 1];
    int j = b0;
    for (; j + 1 < b1; j += 2) {
        int s0 = csc_src[j];
        int s1 = csc_src[j + 1];
        float w0 = csc_w[j];
        float w1 = csc_w[j + 1];
        float v0 = H[(size_t)s0 * DIM + f];
        float v1 = H[(size_t)s1 * DIM + f];
        acc += w0 * v0;
        acc += w1 * v1;
    }
    if (j < b1) {
        int s0 = csc_src[j];
        acc += csc_w[j] * H[(size_t)s0 * DIM + f];
    }
    Out[(size_t)n * DIM + f] = acc + bias[f];
}

__global__ void k_zero(float* __restrict__ p, int n) {
    int i = blockIdx.x * blockDim.x + threadIdx.x;
    if (i < n) p[i] = 0.f;
}

__global__ __launch_bounds__(128) void k_stats_partial(const float* __restrict__ A, const int* __restrict__ gstart,
                                                       float* __restrict__ gsum, float* __restrict__ gsumsq) {
    int g = blockIdx.x / NCHUNK;
    int c = blockIdx.x % NCHUNK;
    int s0 = gstart[g], s1 = gstart[g + 1];
    int len = s1 - s0;
    int a = s0 + (int)((long)len * c / NCHUNK);
    int b = s0 + (int)((long)len * (c + 1) / NCHUNK);
    int f = threadIdx.x;
    float s = 0.f, s2 = 0.f;
    for (int n = a; n < b; ++n) {
        float v = A[(size_t)n * DIM + f];
        s += v;
        s2 += v * v;
    }
    if (b > a) {
        atomicAdd(&gsum[g * DIM + f], s);
        atomicAdd(&gsumsq[g * DIM + f], s2);
    }
}

__global__ void k_stats_final(const float* __restrict__ gsum, const float* __restrict__ gsumsq,
                              const float* __restrict__ cntf, const float* __restrict__ mscale,
                              float* __restrict__ amean, float* __restrict__ rstd) {
    int i = blockIdx.x * blockDim.x + threadIdx.x;
    if (i >= NGRAPH * DIM) return;
    int g = i / DIM, f = i % DIM;
    float cnt = cntf[g];
    float inv = (cnt > 0.f) ? 1.0f / cnt : 0.f;
    float m = gsum[i] * inv;
    float a = mscale[f];
    float var = gsumsq[i] * inv - (2.f * a - a * a) * m * m;
    amean[i] = a * m;
    rstd[i] = rsqrtf(var + EPSV);
}

__global__ void k_norm(const float* __restrict__ A, const int* __restrict__ batch,
                       const float* __restrict__ amean, const float* __restrict__ rstd,
                       const float* __restrict__ gw, const float* __restrict__ gb,
                       const float* __restrict__ res, float* __restrict__ xout) {
    int i = blockIdx.x * blockDim.x + threadIdx.x;  // over N*32 float4 groups
    if (i >= N_NODES * 32) return;
    int n = i >> 5, q = i & 31;
    int g = batch[n];
    float4 v = ((const float4*)A)[i];
    float4 am = ((const float4*)amean)[g * 32 + q];
    float4 rs = ((const float4*)rstd)[g * 32 + q];
    float4 w = ((const float4*)gw)[q];
    float4 b = ((const float4*)gb)[q];
    float4 r = ((const float4*)res)[i];
    float4 o;
    o.x = w.x * (v.x - am.x) * rs.x + b.x;
    o.y = w.y * (v.y - am.y) * rs.y + b.y;
    o.z = w.z * (v.z - am.z) * rs.z + b.z;
    o.w = w.w * (v.w - am.w) * rs.w + b.w;
    o.x = ((o.x > 0.f) ? o.x : expm1f(o.x)) + r.x;
    o.y = ((o.y > 0.f) ? o.y : expm1f(o.y)) + r.y;
    o.z = ((o.z > 0.f) ? o.z : expm1f(o.z)) + r.z;
    o.w = ((o.w > 0.f) ? o.w : expm1f(o.w)) + r.w;
    ((float4*)xout)[i] = o;
}

__global__ __launch_bounds__(128) void k_pool_partial(const float* __restrict__ X, const int* __restrict__ gstart,
                                                      float* __restrict__ pooled) {
    int g = blockIdx.x / NCHUNK;
    int c = blockIdx.x % NCHUNK;
    int s0 = gstart[g], s1 = gstart[g + 1];
    int len = s1 - s0;
    int a = s0 + (int)((long)len * c / NCHUNK);
    int b = s0 + (int)((long)len * (c + 1) / NCHUNK);
    int f = threadIdx.x;
    float s = 0.f;
    for (int n = a; n < b; ++n) s += X[(size_t)n * DIM + f];
    if (b > a) atomicAdd(&pooled[g * DIM + f], s);
}

__global__ __launch_bounds__(128) void k_head(const float* __restrict__ pooled,
                                              const float* __restrict__ w1, const float* __restrict__ b1,
                                              const float* __restrict__ gamma, const float* __restrict__ beta,
                                              const float* __restrict__ rmean, const float* __restrict__ rvar,
                                              const float* __restrict__ w2, const float* __restrict__ b2,
                                              float* __restrict__ zout) {
    __shared__ float sp[DIM];
    __shared__ float sz[DIM];
    int g = blockIdx.x, t = threadIdx.x;
    sp[t] = pooled[g * DIM + t];
    __syncthreads();
    float acc = b1[t];
#pragma unroll 8
    for (int k = 0; k < DIM; k++) acc += sp[k] * w1[k * DIM + t];
    acc = gamma[t] * (acc - rmean[t]) * rsqrtf(rvar[t] + EPSV) + beta[t];
    acc = fmaxf(acc, 0.f);
    sz[t] = acc;
    __syncthreads();
    if (t < NCLS) {
        float a2 = b2[t];
#pragma unroll 8
        for (int k = 0; k < DIM; k++) a2 += sz[k] * w2[k * NCLS + t];
        zout[g * NCLS + t] = a2;
    }
}

// ---------------- launch ----------------

extern "C" void kernel_launch(void* const* d_in, const int* in_sizes, int n_in,
                              void* d_out, int out_size, void* d_ws, size_t ws_size,
                              hipStream_t stream) {
    const float* x_in   = (const float*)d_in[0];
    const int*   ei     = (const int*)d_in[1];
    const int*   batch  = (const int*)d_in[2];
    const float* conv_w = (const float*)d_in[3];
    const float* conv_b = (const float*)d_in[4];
    const float* gn_w   = (const float*)d_in[5];
    const float* gn_b   = (const float*)d_in[6];
    const float* gn_ms  = (const float*)d_in[7];
    const float* w1     = (const float*)d_in[8];
    const float* b1     = (const float*)d_in[9];
    const float* bng    = (const float*)d_in[10];
    const float* bnb    = (const float*)d_in[11];
    const float* bnm    = (const float*)d_in[12];
    const float* bnv    = (const float*)d_in[13];
    const float* w2     = (const float*)d_in[14];
    const float* b2     = (const float*)d_in[15];

    float* out_x = (float*)d_out;
    float* out_z = out_x + (size_t)N_NODES * DIM;

    char* ws = (char*)d_ws;
    size_t off = 0;
    auto alloc = [&](size_t bytes) -> void* {
        void* p = ws + off;
        off += (bytes + 255) / 256 * 256;
        return p;
    };
    float* h       = (float*)alloc(sizeof(float) * (size_t)N_NODES * DIM);
    float* agg     = (float*)alloc(sizeof(float) * (size_t)N_NODES * DIM);
    int*   csc_src = (int*)alloc(sizeof(int) * (size_t)N_EDGES);
    float* csc_w   = (float*)alloc(sizeof(float) * (size_t)N_EDGES);
    int*   deg     = (int*)alloc(sizeof(int) * N_NODES);
    float* dis     = (float*)alloc(sizeof(float) * N_NODES);
    int*   cursor  = (int*)alloc(sizeof(int) * N_NODES);
    int*   rowoff  = (int*)alloc(sizeof(int) * (N_NODES + 1));
    int*   bsum    = (int*)alloc(sizeof(int) * SCAN_NB);
    int*   boff    = (int*)alloc(sizeof(int) * SCAN_NB);
    float* cntf    = (float*)alloc(sizeof(float) * NGRAPH);
    int*   gstart  = (int*)alloc(sizeof(int) * (NGRAPH + 1));
    float* gsum    = (float*)alloc(sizeof(float) * 2 * NGRAPH * DIM);  // gsum | gsumsq contiguous
    float* gsumsq  = gsum + NGRAPH * DIM;
    float* amean   = (float*)alloc(sizeof(float) * NGRAPH * DIM);
    float* rstd    = (float*)alloc(sizeof(float) * NGRAPH * DIM);
    float* pooled  = (float*)alloc(sizeof(float) * NGRAPH * DIM);

    // ---- prepass: degrees, graph offsets, CSC build ----
    k_init<<<(N_NODES + 255) / 256, 256, 0, stream>>>(deg, cursor);
    k_edge_deg<<<(N_EDGES + 255) / 256, 256, 0, stream>>>(ei, deg);
    k_node_dis<<<(N_NODES + 255) / 256, 256, 0, stream>>>(deg, dis);
    k_gbound<<<(N_NODES + 255) / 256, 256, 0, stream>>>(batch, gstart);
    k_scan_bsum<<<SCAN_NB, SCAN_B, 0, stream>>>(deg, bsum);
    k_scan_mid<<<1, 256, 0, stream>>>(bsum, boff, gstart, cntf);
    k_scan_final<<<SCAN_NB, SCAN_B, 0, stream>>>(deg, boff, rowoff);
    k_build_csc<<<(N_EDGES + 255) / 256, 256, 0, stream>>>(ei, dis, rowoff, cursor, csc_src, csc_w);

    // ---- layers ----
    const float* xcur = x_in;
    for (int l = 0; l < NLAYERS; l++) {
        k_gemm<<<N_NODES / GEMM_ROWS, 256, 0, stream>>>(xcur, conv_w + (size_t)l * DIM * DIM, h);
        k_aggregate<<<N_NODES, 128, 0, stream>>>(h, csc_src, csc_w, rowoff, dis, conv_b + (size_t)l * DIM, agg);
        k_zero<<<(2 * NGRAPH * DIM + 255) / 256, 256, 0, stream>>>(gsum, 2 * NGRAPH * DIM);
        k_stats_partial<<<NGRAPH * NCHUNK, 128, 0, stream>>>(agg, gstart, gsum, gsumsq);
        k_stats_final<<<(NGRAPH * DIM + 255) / 256, 256, 0, stream>>>(gsum, gsumsq, cntf, gn_ms + (size_t)l * DIM,
                                                                      amean, rstd);
        k_norm<<<(N_NODES * 32 + 255) / 256, 256, 0, stream>>>(agg, batch, amean, rstd, gn_w + (size_t)l * DIM,
                                                               gn_b + (size_t)l * DIM, xcur, out_x);
        xcur = out_x;
    }

    // ---- pool + head ----
    k_zero<<<(NGRAPH * DIM + 255) / 256, 256, 0, stream>>>(pooled, NGRAPH * DIM);
    k_pool_partial<<<NGRAPH * NCHUNK, 128, 0, stream>>>(out_x, gstart, pooled);
    k_head<<<NGRAPH, DIM, 0, stream>>>(pooled, w1, b1, bng, bnb, bnm, bnv, w2, b2, out_z);
}

// Round 3
// 1143.844 us; speedup vs baseline: 1.3279x; 1.0937x over previous
//
#include <hip/hip_runtime.h>
#include <stdint.h>

#define N_NODES 100000
#define N_EDGES 1600000
#define DIM 128
#define NLAYERS 4
#define NGRAPH 128
#define NCLS 10
#define EPSV 1e-5f

#define SCAN_B 512
#define SCAN_NB ((N_NODES + SCAN_B - 1) / SCAN_B)   // 196
#define NCHUNK 16
#define GEMM_ROWS 32

// ---------------- bf16 helpers ----------------

__device__ __forceinline__ float bf_lo(uint32_t u) { return __uint_as_float(u << 16); }
__device__ __forceinline__ float bf_hi(uint32_t u) { return __uint_as_float(u & 0xffff0000u); }
__device__ __forceinline__ uint32_t f2bf_rne(float f) {
    uint32_t x = __float_as_uint(f);
    return (x + 0x7fffu + ((x >> 16) & 1u)) >> 16;
}
__device__ __forceinline__ uint32_t pack_bf2(float a, float b) {
    return f2bf_rne(a) | (f2bf_rne(b) << 16);
}

// ---------------- prepass kernels ----------------

__global__ void k_init(int* __restrict__ deg, int* __restrict__ cursor) {
    int i = blockIdx.x * blockDim.x + threadIdx.x;
    if (i < N_NODES) { deg[i] = 1; cursor[i] = 0; }
}

__global__ void k_edge_deg(const int* __restrict__ ei, int* __restrict__ deg) {
    int e = blockIdx.x * blockDim.x + threadIdx.x;
    if (e < N_EDGES) atomicAdd(&deg[ei[N_EDGES + e]], 1);
}

__global__ void k_node_dis(const int* __restrict__ deg, float* __restrict__ dis) {
    int i = blockIdx.x * blockDim.x + threadIdx.x;
    if (i < N_NODES) dis[i] = rsqrtf((float)deg[i]);
}

// graph segment boundaries from the SORTED batch array — no atomics
__global__ void k_gbound(const int* __restrict__ batch, int* __restrict__ gstart) {
    int i = blockIdx.x * blockDim.x + threadIdx.x;
    if (i >= N_NODES) return;
    int b = batch[i];
    if (i == 0) {
        for (int g = 0; g <= b; g++) gstart[g] = 0;
    } else {
        int bp = batch[i - 1];
        for (int g = bp + 1; g <= b; g++) gstart[g] = i;
    }
    if (i == N_NODES - 1) {
        for (int g = b + 1; g <= NGRAPH; g++) gstart[g] = N_NODES;
    }
}

__global__ __launch_bounds__(SCAN_B) void k_scan_bsum(const int* __restrict__ deg, int* __restrict__ bsum) {
    __shared__ int s[SCAN_B];
    int t = threadIdx.x;
    int n = blockIdx.x * SCAN_B + t;
    int v = (n < N_NODES) ? deg[n] - 1 : 0;
    s[t] = v; __syncthreads();
    for (int off = SCAN_B / 2; off > 0; off >>= 1) {
        if (t < off) s[t] += s[t + off];
        __syncthreads();
    }
    if (t == 0) bsum[blockIdx.x] = s[0];
}

__global__ __launch_bounds__(256) void k_scan_mid(const int* __restrict__ bsum, int* __restrict__ boff,
                                                  const int* __restrict__ gstart, float* __restrict__ cntf) {
    __shared__ int s[256];
    int t = threadIdx.x;
    int v = (t < SCAN_NB) ? bsum[t] : 0;
    s[t] = v; __syncthreads();
    for (int off = 1; off < 256; off <<= 1) {
        int a = (t >= off) ? s[t - off] : 0;
        __syncthreads();
        s[t] += a;
        __syncthreads();
    }
    if (t < SCAN_NB) boff[t] = s[t] - v;
    if (t < NGRAPH) cntf[t] = (float)(gstart[t + 1] - gstart[t]);
}

__global__ __launch_bounds__(SCAN_B) void k_scan_final(const int* __restrict__ deg, const int* __restrict__ boff,
                                                       int* __restrict__ rowoff) {
    __shared__ int s[SCAN_B];
    int t = threadIdx.x;
    int n = blockIdx.x * SCAN_B + t;
    int v = (n < N_NODES) ? deg[n] - 1 : 0;
    s[t] = v; __syncthreads();
    for (int off = 1; off < SCAN_B; off <<= 1) {
        int a = (t >= off) ? s[t - off] : 0;
        __syncthreads();
        s[t] += a;
        __syncthreads();
    }
    int excl = s[t] - v;
    if (n <= N_NODES) rowoff[n] = boff[blockIdx.x] + excl;
}

__global__ void k_build_csc(const int* __restrict__ ei, const float* __restrict__ dis,
                            const int* __restrict__ rowoff, int* __restrict__ cursor,
                            int* __restrict__ csc_src, float* __restrict__ csc_w) {
    int e = blockIdx.x * blockDim.x + threadIdx.x;
    if (e >= N_EDGES) return;
    int s = ei[e];
    int d = ei[N_EDGES + e];
    int pos = rowoff[d] + atomicAdd(&cursor[d], 1);
    csc_src[pos] = s;
    csc_w[pos] = dis[s] * dis[d];
}

// ---------------- per-layer kernels ----------------

// H[N,128](bf16) = X[N,128](f32) @ W[128,128](f32); 32 rows/block, 256 thr, 4x4/thr
__global__ __launch_bounds__(256) void k_gemm(const float* __restrict__ X, const float* __restrict__ W,
                                              uint32_t* __restrict__ H) {
    __shared__ float sX[GEMM_ROWS][DIM];
    __shared__ float sW[64][DIM];
    int t = threadIdx.x;
    size_t row0 = (size_t)blockIdx.x * GEMM_ROWS;

    const float4* Xv = (const float4*)(X + row0 * DIM);
    float4* sXv = (float4*)&sX[0][0];
#pragma unroll
    for (int i = 0; i < 4; i++) sXv[t + 256 * i] = Xv[t + 256 * i];

    float4 acc[4];
#pragma unroll
    for (int r = 0; r < 4; r++) acc[r] = make_float4(0.f, 0.f, 0.f, 0.f);

    int tc = (t & 31) * 4;
    int tr = (t >> 5) * 4;

    for (int kb = 0; kb < 2; ++kb) {
        __syncthreads();
        const float4* Wv = (const float4*)(W + (size_t)kb * 64 * DIM);
        float4* sWv = (float4*)&sW[0][0];
#pragma unroll
        for (int i = 0; i < 8; i++) sWv[t + 256 * i] = Wv[t + 256 * i];
        __syncthreads();
#pragma unroll 4
        for (int k = 0; k < 64; k += 4) {
            float4 xr[4];
#pragma unroll
            for (int r = 0; r < 4; r++) xr[r] = *(const float4*)&sX[tr + r][kb * 64 + k];
#pragma unroll
            for (int j = 0; j < 4; j++) {
                float4 wv = *(const float4*)&sW[k + j][tc];
#pragma unroll
                for (int r = 0; r < 4; r++) {
                    float xv = (j == 0) ? xr[r].x : (j == 1) ? xr[r].y : (j == 2) ? xr[r].z : xr[r].w;
                    acc[r].x += xv * wv.x;
                    acc[r].y += xv * wv.y;
                    acc[r].z += xv * wv.z;
                    acc[r].w += xv * wv.w;
                }
            }
        }
    }
    // epilogue: pack to bf16 (2 features per uint), row stride 64 uints
    uint32_t* Hb = H + row0 * 64;
#pragma unroll
    for (int r = 0; r < 4; r++) {
        uint2 p;
        p.x = pack_bf2(acc[r].x, acc[r].y);
        p.y = pack_bf2(acc[r].z, acc[r].w);
        *(uint2*)&Hb[(size_t)(tr + r) * 64 + (tc >> 1)] = p;
    }
}

// pull-based aggregation over bf16 H: ONE WAVE per dst node, 4 nodes/block.
// lane L handles features 2L, 2L+1 (one uint = 2 bf16 per row per lane).
__global__ __launch_bounds__(256) void k_aggregate(const uint32_t* __restrict__ H,
                                                   const int* __restrict__ csc_src,
                                                   const float* __restrict__ csc_w,
                                                   const int* __restrict__ rowoff,
                                                   const float* __restrict__ dis,
                                                   const float* __restrict__ bias,
                                                   float* __restrict__ Out) {
    int wid = threadIdx.x >> 6;
    int lane = threadIdx.x & 63;
    int n = blockIdx.x * 4 + wid;     // grid = N/4 exactly

    float self = dis[n];
    float sw = self * self;
    uint32_t us = H[(size_t)n * 64 + lane];
    float a0 = sw * bf_lo(us);
    float a1 = sw * bf_hi(us);

    int b0 = rowoff[n], b1 = rowoff[n + 1];
    int j = b0;
    for (; j + 1 < b1; j += 2) {
        int s0 = csc_src[j];
        int s1 = csc_src[j + 1];
        float w0 = csc_w[j];
        float w1 = csc_w[j + 1];
        uint32_t u0 = H[(size_t)s0 * 64 + lane];
        uint32_t u1 = H[(size_t)s1 * 64 + lane];
        a0 += w0 * bf_lo(u0);
        a1 += w0 * bf_hi(u0);
        a0 += w1 * bf_lo(u1);
        a1 += w1 * bf_hi(u1);
    }
    if (j < b1) {
        int s0 = csc_src[j];
        float w0 = csc_w[j];
        uint32_t u0 = H[(size_t)s0 * 64 + lane];
        a0 += w0 * bf_lo(u0);
        a1 += w0 * bf_hi(u0);
    }
    float2 bb = ((const float2*)bias)[lane];
    ((float2*)&Out[(size_t)n * DIM])[lane] = make_float2(a0 + bb.x, a1 + bb.y);
}

__global__ void k_zero(float* __restrict__ p, int n) {
    int i = blockIdx.x * blockDim.x + threadIdx.x;
    if (i < n) p[i] = 0.f;
}

__global__ __launch_bounds__(128) void k_stats_partial(const float* __restrict__ A, const int* __restrict__ gstart,
                                                       float* __restrict__ gsum, float* __restrict__ gsumsq) {
    int g = blockIdx.x / NCHUNK;
    int c = blockIdx.x % NCHUNK;
    int s0 = gstart[g], s1 = gstart[g + 1];
    int len = s1 - s0;
    int a = s0 + (int)((long)len * c / NCHUNK);
    int b = s0 + (int)((long)len * (c + 1) / NCHUNK);
    int f = threadIdx.x;
    float s = 0.f, s2 = 0.f;
    for (int n = a; n < b; ++n) {
        float v = A[(size_t)n * DIM + f];
        s += v;
        s2 += v * v;
    }
    if (b > a) {
        atomicAdd(&gsum[g * DIM + f], s);
        atomicAdd(&gsumsq[g * DIM + f], s2);
    }
}

__global__ void k_stats_final(const float* __restrict__ gsum, const float* __restrict__ gsumsq,
                              const float* __restrict__ cntf, const float* __restrict__ mscale,
                              float* __restrict__ amean, float* __restrict__ rstd) {
    int i = blockIdx.x * blockDim.x + threadIdx.x;
    if (i >= NGRAPH * DIM) return;
    int g = i / DIM, f = i % DIM;
    float cnt = cntf[g];
    float inv = (cnt > 0.f) ? 1.0f / cnt : 0.f;
    float m = gsum[i] * inv;
    float a = mscale[f];
    float var = gsumsq[i] * inv - (2.f * a - a * a) * m * m;
    amean[i] = a * m;
    rstd[i] = rsqrtf(var + EPSV);
}

__global__ void k_norm(const float* __restrict__ A, const int* __restrict__ batch,
                       const float* __restrict__ amean, const float* __restrict__ rstd,
                       const float* __restrict__ gw, const float* __restrict__ gb,
                       const float* __restrict__ res, float* __restrict__ xout) {
    int i = blockIdx.x * blockDim.x + threadIdx.x;  // over N*32 float4 groups
    if (i >= N_NODES * 32) return;
    int n = i >> 5, q = i & 31;
    int g = batch[n];
    float4 v = ((const float4*)A)[i];
    float4 am = ((const float4*)amean)[g * 32 + q];
    float4 rs = ((const float4*)rstd)[g * 32 + q];
    float4 w = ((const float4*)gw)[q];
    float4 b = ((const float4*)gb)[q];
    float4 r = ((const float4*)res)[i];
    float4 o;
    o.x = w.x * (v.x - am.x) * rs.x + b.x;
    o.y = w.y * (v.y - am.y) * rs.y + b.y;
    o.z = w.z * (v.z - am.z) * rs.z + b.z;
    o.w = w.w * (v.w - am.w) * rs.w + b.w;
    o.x = ((o.x > 0.f) ? o.x : expm1f(o.x)) + r.x;
    o.y = ((o.y > 0.f) ? o.y : expm1f(o.y)) + r.y;
    o.z = ((o.z > 0.f) ? o.z : expm1f(o.z)) + r.z;
    o.w = ((o.w > 0.f) ? o.w : expm1f(o.w)) + r.w;
    ((float4*)xout)[i] = o;
}

__global__ __launch_bounds__(128) void k_pool_partial(const float* __restrict__ X, const int* __restrict__ gstart,
                                                      float* __restrict__ pooled) {
    int g = blockIdx.x / NCHUNK;
    int c = blockIdx.x % NCHUNK;
    int s0 = gstart[g], s1 = gstart[g + 1];
    int len = s1 - s0;
    int a = s0 + (int)((long)len * c / NCHUNK);
    int b = s0 + (int)((long)len * (c + 1) / NCHUNK);
    int f = threadIdx.x;
    float s = 0.f;
    for (int n = a; n < b; ++n) s += X[(size_t)n * DIM + f];
    if (b > a) atomicAdd(&pooled[g * DIM + f], s);
}

__global__ __launch_bounds__(128) void k_head(const float* __restrict__ pooled,
                                              const float* __restrict__ w1, const float* __restrict__ b1,
                                              const float* __restrict__ gamma, const float* __restrict__ beta,
                                              const float* __restrict__ rmean, const float* __restrict__ rvar,
                                              const float* __restrict__ w2, const float* __restrict__ b2,
                                              float* __restrict__ zout) {
    __shared__ float sp[DIM];
    __shared__ float sz[DIM];
    int g = blockIdx.x, t = threadIdx.x;
    sp[t] = pooled[g * DIM + t];
    __syncthreads();
    float acc = b1[t];
#pragma unroll 8
    for (int k = 0; k < DIM; k++) acc += sp[k] * w1[k * DIM + t];
    acc = gamma[t] * (acc - rmean[t]) * rsqrtf(rvar[t] + EPSV) + beta[t];
    acc = fmaxf(acc, 0.f);
    sz[t] = acc;
    __syncthreads();
    if (t < NCLS) {
        float a2 = b2[t];
#pragma unroll 8
        for (int k = 0; k < DIM; k++) a2 += sz[k] * w2[k * NCLS + t];
        zout[g * NCLS + t] = a2;
    }
}

// ---------------- launch ----------------

extern "C" void kernel_launch(void* const* d_in, const int* in_sizes, int n_in,
                              void* d_out, int out_size, void* d_ws, size_t ws_size,
                              hipStream_t stream) {
    const float* x_in   = (const float*)d_in[0];
    const int*   ei     = (const int*)d_in[1];
    const int*   batch  = (const int*)d_in[2];
    const float* conv_w = (const float*)d_in[3];
    const float* conv_b = (const float*)d_in[4];
    const float* gn_w   = (const float*)d_in[5];
    const float* gn_b   = (const float*)d_in[6];
    const float* gn_ms  = (const float*)d_in[7];
    const float* w1     = (const float*)d_in[8];
    const float* b1     = (const float*)d_in[9];
    const float* bng    = (const float*)d_in[10];
    const float* bnb    = (const float*)d_in[11];
    const float* bnm    = (const float*)d_in[12];
    const float* bnv    = (const float*)d_in[13];
    const float* w2     = (const float*)d_in[14];
    const float* b2     = (const float*)d_in[15];

    float* out_x = (float*)d_out;
    float* out_z = out_x + (size_t)N_NODES * DIM;

    char* ws = (char*)d_ws;
    size_t off = 0;
    auto alloc = [&](size_t bytes) -> void* {
        void* p = ws + off;
        off += (bytes + 255) / 256 * 256;
        return p;
    };
    uint32_t* h     = (uint32_t*)alloc(sizeof(uint32_t) * (size_t)N_NODES * 64);  // bf16 H
    float* agg      = (float*)alloc(sizeof(float) * (size_t)N_NODES * DIM);
    int*   csc_src  = (int*)alloc(sizeof(int) * (size_t)N_EDGES);
    float* csc_w    = (float*)alloc(sizeof(float) * (size_t)N_EDGES);
    int*   deg      = (int*)alloc(sizeof(int) * N_NODES);
    float* dis      = (float*)alloc(sizeof(float) * N_NODES);
    int*   cursor   = (int*)alloc(sizeof(int) * N_NODES);
    int*   rowoff   = (int*)alloc(sizeof(int) * (N_NODES + 1));
    int*   bsum     = (int*)alloc(sizeof(int) * SCAN_NB);
    int*   boff     = (int*)alloc(sizeof(int) * SCAN_NB);
    float* cntf     = (float*)alloc(sizeof(float) * NGRAPH);
    int*   gstart   = (int*)alloc(sizeof(int) * (NGRAPH + 1));
    float* gsum     = (float*)alloc(sizeof(float) * 2 * NGRAPH * DIM);
    float* gsumsq   = gsum + NGRAPH * DIM;
    float* amean    = (float*)alloc(sizeof(float) * NGRAPH * DIM);
    float* rstd     = (float*)alloc(sizeof(float) * NGRAPH * DIM);
    float* pooled   = (float*)alloc(sizeof(float) * NGRAPH * DIM);

    // ---- prepass ----
    k_init<<<(N_NODES + 255) / 256, 256, 0, stream>>>(deg, cursor);
    k_edge_deg<<<(N_EDGES + 255) / 256, 256, 0, stream>>>(ei, deg);
    k_node_dis<<<(N_NODES + 255) / 256, 256, 0, stream>>>(deg, dis);
    k_gbound<<<(N_NODES + 255) / 256, 256, 0, stream>>>(batch, gstart);
    k_scan_bsum<<<SCAN_NB, SCAN_B, 0, stream>>>(deg, bsum);
    k_scan_mid<<<1, 256, 0, stream>>>(bsum, boff, gstart, cntf);
    k_scan_final<<<SCAN_NB, SCAN_B, 0, stream>>>(deg, boff, rowoff);
    k_build_csc<<<(N_EDGES + 255) / 256, 256, 0, stream>>>(ei, dis, rowoff, cursor, csc_src, csc_w);

    // ---- layers ----
    const float* xcur = x_in;
    for (int l = 0; l < NLAYERS; l++) {
        k_gemm<<<N_NODES / GEMM_ROWS, 256, 0, stream>>>(xcur, conv_w + (size_t)l * DIM * DIM, h);
        k_aggregate<<<N_NODES / 4, 256, 0, stream>>>(h, csc_src, csc_w, rowoff, dis, conv_b + (size_t)l * DIM, agg);
        k_zero<<<(2 * NGRAPH * DIM + 255) / 256, 256, 0, stream>>>(gsum, 2 * NGRAPH * DIM);
        k_stats_partial<<<NGRAPH * NCHUNK, 128, 0, stream>>>(agg, gstart, gsum, gsumsq);
        k_stats_final<<<(NGRAPH * DIM + 255) / 256, 256, 0, stream>>>(gsum, gsumsq, cntf, gn_ms + (size_t)l * DIM,
                                                                      amean, rstd);
        k_norm<<<(N_NODES * 32 + 255) / 256, 256, 0, stream>>>(agg, batch, amean, rstd, gn_w + (size_t)l * DIM,
                                                               gn_b + (size_t)l * DIM, xcur, out_x);
        xcur = out_x;
    }

    // ---- pool + head ----
    k_zero<<<(NGRAPH * DIM + 255) / 256, 256, 0, stream>>>(pooled, NGRAPH * DIM);
    k_pool_partial<<<NGRAPH * NCHUNK, 128, 0, stream>>>(out_x, gstart, pooled);
    k_head<<<NGRAPH, DIM, 0, stream>>>(pooled, w1, b1, bng, bnb, bnm, bnv, w2, b2, out_z);
}

// Round 4
// 1074.924 us; speedup vs baseline: 1.4131x; 1.0641x over previous
//
#include <hip/hip_runtime.h>
#include <stdint.h>

#define N_NODES 100000
#define N_PAD   100032            // 1563 * 64, padded rows for MFMA GEMM
#define N_EDGES 1600000
#define DIM 128
#define NLAYERS 4
#define NGRAPH 128
#define NCLS 10
#define EPSV 1e-5f

#define SCAN_B 512
#define SCAN_NB ((N_NODES + SCAN_B - 1) / SCAN_B)   // 196
#define NCHUNK 16

typedef __attribute__((ext_vector_type(8))) short short8_t;   // 8 bf16
typedef __attribute__((ext_vector_type(4))) float float4_t;   // 4 fp32 acc

// ---------------- bf16 helpers ----------------

__device__ __forceinline__ float bf_lo(uint32_t u) { return __uint_as_float(u << 16); }
__device__ __forceinline__ float bf_hi(uint32_t u) { return __uint_as_float(u & 0xffff0000u); }
__device__ __forceinline__ uint32_t f2bf_rne(float f) {
    uint32_t x = __float_as_uint(f);
    return (x + 0x7fffu + ((x >> 16) & 1u)) >> 16;
}
__device__ __forceinline__ uint32_t pack_bf2(float a, float b) {
    return f2bf_rne(a) | (f2bf_rne(b) << 16);
}

// ---------------- prepass kernels ----------------

__global__ void k_init(int* __restrict__ deg, int* __restrict__ cursor) {
    int i = blockIdx.x * blockDim.x + threadIdx.x;
    if (i < N_NODES) { deg[i] = 1; cursor[i] = 0; }
}

__global__ void k_edge_deg(const int* __restrict__ ei, int* __restrict__ deg) {
    int e = blockIdx.x * blockDim.x + threadIdx.x;
    if (e < N_EDGES) atomicAdd(&deg[ei[N_EDGES + e]], 1);
}

__global__ void k_node_dis(const int* __restrict__ deg, float* __restrict__ dis) {
    int i = blockIdx.x * blockDim.x + threadIdx.x;
    if (i < N_NODES) dis[i] = rsqrtf((float)deg[i]);
}

// graph segment boundaries from the SORTED batch array — no atomics
__global__ void k_gbound(const int* __restrict__ batch, int* __restrict__ gstart) {
    int i = blockIdx.x * blockDim.x + threadIdx.x;
    if (i >= N_NODES) return;
    int b = batch[i];
    if (i == 0) {
        for (int g = 0; g <= b; g++) gstart[g] = 0;
    } else {
        int bp = batch[i - 1];
        for (int g = bp + 1; g <= b; g++) gstart[g] = i;
    }
    if (i == N_NODES - 1) {
        for (int g = b + 1; g <= NGRAPH; g++) gstart[g] = N_NODES;
    }
}

__global__ __launch_bounds__(SCAN_B) void k_scan_bsum(const int* __restrict__ deg, int* __restrict__ bsum) {
    __shared__ int s[SCAN_B];
    int t = threadIdx.x;
    int n = blockIdx.x * SCAN_B + t;
    int v = (n < N_NODES) ? deg[n] - 1 : 0;
    s[t] = v; __syncthreads();
    for (int off = SCAN_B / 2; off > 0; off >>= 1) {
        if (t < off) s[t] += s[t + off];
        __syncthreads();
    }
    if (t == 0) bsum[blockIdx.x] = s[0];
}

__global__ __launch_bounds__(256) void k_scan_mid(const int* __restrict__ bsum, int* __restrict__ boff) {
    __shared__ int s[256];
    int t = threadIdx.x;
    int v = (t < SCAN_NB) ? bsum[t] : 0;
    s[t] = v; __syncthreads();
    for (int off = 1; off < 256; off <<= 1) {
        int a = (t >= off) ? s[t - off] : 0;
        __syncthreads();
        s[t] += a;
        __syncthreads();
    }
    if (t < SCAN_NB) boff[t] = s[t] - v;
}

__global__ __launch_bounds__(SCAN_B) void k_scan_final(const int* __restrict__ deg, const int* __restrict__ boff,
                                                       int* __restrict__ rowoff) {
    __shared__ int s[SCAN_B];
    int t = threadIdx.x;
    int n = blockIdx.x * SCAN_B + t;
    int v = (n < N_NODES) ? deg[n] - 1 : 0;
    s[t] = v; __syncthreads();
    for (int off = 1; off < SCAN_B; off <<= 1) {
        int a = (t >= off) ? s[t - off] : 0;
        __syncthreads();
        s[t] += a;
        __syncthreads();
    }
    int excl = s[t] - v;
    if (n <= N_NODES) rowoff[n] = boff[blockIdx.x] + excl;
}

__global__ void k_build_csc(const int* __restrict__ ei, const float* __restrict__ dis,
                            const int* __restrict__ rowoff, int* __restrict__ cursor,
                            int* __restrict__ csc_src, float* __restrict__ csc_w) {
    int e = blockIdx.x * blockDim.x + threadIdx.x;
    if (e >= N_EDGES) return;
    int s = ei[e];
    int d = ei[N_EDGES + e];
    int pos = rowoff[d] + atomicAdd(&cursor[d], 1);
    csc_src[pos] = s;
    csc_w[pos] = dis[s] * dis[d];
}

// cast conv_w (fp32, [L][K][N]) -> Wt (bf16, [L][N][K] packed as uint pairs along K)
__global__ void k_cast_w(const float* __restrict__ W, uint32_t* __restrict__ Wt) {
    int i = blockIdx.x * blockDim.x + threadIdx.x;    // over L*128*64
    if (i >= NLAYERS * DIM * 64) return;
    int l = i / (DIM * 64);
    int n = (i / 64) % DIM;
    int ku = i % 64;
    const float* Wl = W + (size_t)l * DIM * DIM;
    float w0 = Wl[(2 * ku) * DIM + n];
    float w1 = Wl[(2 * ku + 1) * DIM + n];
    Wt[i] = pack_bf2(w0, w1);
}

// cast x (fp32 [N][128]) -> Xb (bf16, uint pairs)
__global__ void k_cast_x(const float* __restrict__ X, uint32_t* __restrict__ Xb) {
    int i = blockIdx.x * blockDim.x + threadIdx.x;    // over N*64
    if (i >= N_NODES * 64) return;
    float2 v = ((const float2*)X)[i];
    Xb[i] = pack_bf2(v.x, v.y);
}

// ---------------- per-layer kernels ----------------

// H[64 rows][128] bf16 = Xb @ Wt via mfma_f32_16x16x32_bf16.
// 256 thr = 4 waves; wave w computes rows w*16..w*16+15, all 128 cols (8 tiles).
__global__ __launch_bounds__(256) void k_gemm_mfma(const uint32_t* __restrict__ Xb,
                                                   const uint32_t* __restrict__ Wt,
                                                   uint32_t* __restrict__ H) {
    __shared__ float tile[64][132];   // 132 stride: quad rows 2-way bank alias only (free)
    int t = threadIdx.x;
    int wid = t >> 6;
    int lane = t & 63;
    int quad = lane >> 4;
    int s15 = lane & 15;
    size_t row_base = (size_t)blockIdx.x * 64 + wid * 16;

    float4_t acc[8];
#pragma unroll
    for (int i = 0; i < 8; i++) acc[i] = (float4_t){0.f, 0.f, 0.f, 0.f};

    const uint32_t* arow = Xb + (row_base + s15) * 64 + quad * 4;
#pragma unroll
    for (int kk = 0; kk < 4; kk++) {
        uint4 au = *(const uint4*)(arow + kk * 16);
        short8_t a = __builtin_bit_cast(short8_t, au);
#pragma unroll
        for (int nt = 0; nt < 8; nt++) {
            uint4 bu = *(const uint4*)(Wt + (size_t)(nt * 16 + s15) * 64 + kk * 16 + quad * 4);
            short8_t b = __builtin_bit_cast(short8_t, bu);
            acc[nt] = __builtin_amdgcn_mfma_f32_16x16x32_bf16(a, b, acc[nt], 0, 0, 0);
        }
    }
    // C layout: col = lane&15, row = quad*4 + reg
#pragma unroll
    for (int nt = 0; nt < 8; nt++) {
#pragma unroll
        for (int r = 0; r < 4; r++) {
            tile[wid * 16 + quad * 4 + r][nt * 16 + s15] = acc[nt][r];
        }
    }
    __syncthreads();
    uint32_t* Hb = H + (size_t)blockIdx.x * 64 * 64;
#pragma unroll
    for (int i = 0; i < 16; i++) {
        int idx = t + 256 * i;            // over 4096 uints
        int row = idx >> 6, cu = idx & 63;
        float2 v = *(const float2*)&tile[row][cu * 2];
        Hb[(size_t)row * 64 + cu] = pack_bf2(v.x, v.y);
    }
}

// pull aggregation: 1 wave per node, quarter-wave rows.
// lane = quad*16 + s15; each lane loads uint4 = 8 bf16 features [s15*8 .. s15*8+7];
// quad q handles edge j+q -> 4 edges per loop step, x2 unroll = 8.
__global__ __launch_bounds__(256) void k_aggregate(const uint32_t* __restrict__ H,
                                                   const int* __restrict__ csc_src,
                                                   const float* __restrict__ csc_w,
                                                   const int* __restrict__ rowoff,
                                                   const float* __restrict__ dis,
                                                   const float* __restrict__ bias,
                                                   float* __restrict__ Out) {
    int wid = threadIdx.x >> 6;
    int lane = threadIdx.x & 63;
    int q = lane >> 4;
    int s = lane & 15;
    int n = blockIdx.x * 4 + wid;     // grid = N/4 exactly

    float acc[8];
    {
        float d = dis[n];
        float sw = (q == 0) ? d * d : 0.f;     // self term counted once (quad 0)
        uint4 us = ((const uint4*)(H + (size_t)n * 64))[s];
        acc[0] = sw * bf_lo(us.x); acc[1] = sw * bf_hi(us.x);
        acc[2] = sw * bf_lo(us.y); acc[3] = sw * bf_hi(us.y);
        acc[4] = sw * bf_lo(us.z); acc[5] = sw * bf_hi(us.z);
        acc[6] = sw * bf_lo(us.w); acc[7] = sw * bf_hi(us.w);
    }

    int b0 = rowoff[n], b1 = rowoff[n + 1];
    for (int j = b0; j < b1; j += 8) {
        int e0 = j + q;
        int e1 = j + 4 + q;
        int i0 = (e0 < b1) ? csc_src[e0] : n;
        float w0 = (e0 < b1) ? csc_w[e0] : 0.f;
        int i1 = (e1 < b1) ? csc_src[e1] : n;
        float w1 = (e1 < b1) ? csc_w[e1] : 0.f;
        uint4 u0 = ((const uint4*)(H + (size_t)i0 * 64))[s];
        uint4 u1 = ((const uint4*)(H + (size_t)i1 * 64))[s];
        acc[0] += w0 * bf_lo(u0.x); acc[1] += w0 * bf_hi(u0.x);
        acc[2] += w0 * bf_lo(u0.y); acc[3] += w0 * bf_hi(u0.y);
        acc[4] += w0 * bf_lo(u0.z); acc[5] += w0 * bf_hi(u0.z);
        acc[6] += w0 * bf_lo(u0.w); acc[7] += w0 * bf_hi(u0.w);
        acc[0] += w1 * bf_lo(u1.x); acc[1] += w1 * bf_hi(u1.x);
        acc[2] += w1 * bf_lo(u1.y); acc[3] += w1 * bf_hi(u1.y);
        acc[4] += w1 * bf_lo(u1.z); acc[5] += w1 * bf_hi(u1.z);
        acc[6] += w1 * bf_lo(u1.w); acc[7] += w1 * bf_hi(u1.w);
    }
    // combine quarters
#pragma unroll
    for (int k = 0; k < 8; k++) {
        acc[k] += __shfl_xor(acc[k], 16);
        acc[k] += __shfl_xor(acc[k], 32);
    }
    // lane (q,s) writes features s*8 + 2q, s*8 + 2q + 1  -> fully coalesced 512B
    float o0 = (q == 0) ? acc[0] : (q == 1) ? acc[2] : (q == 2) ? acc[4] : acc[6];
    float o1 = (q == 0) ? acc[1] : (q == 1) ? acc[3] : (q == 2) ? acc[5] : acc[7];
    float2 bb = ((const float2*)bias)[s * 4 + q];
    ((float2*)(Out + (size_t)n * DIM))[s * 4 + q] = make_float2(o0 + bb.x, o1 + bb.y);
}

// GraphNorm stats: one block per graph, 512 thr (4 row-parts x 128 features)
__global__ __launch_bounds__(512) void k_stats(const float* __restrict__ A, const int* __restrict__ gstart,
                                               const float* __restrict__ mscale,
                                               float* __restrict__ amean, float* __restrict__ rstd) {
    __shared__ float L1[4][DIM];
    __shared__ float L2[4][DIM];
    int g = blockIdx.x;
    int t = threadIdx.x;
    int f = t & 127;
    int p = t >> 7;
    int s0 = gstart[g], s1 = gstart[g + 1];
    float s = 0.f, s2 = 0.f;
    for (int n = s0 + p; n < s1; n += 4) {
        float v = A[(size_t)n * DIM + f];
        s += v;
        s2 += v * v;
    }
    L1[p][f] = s; L2[p][f] = s2;
    __syncthreads();
    if (p == 0) {
        s = L1[0][f] + L1[1][f] + L1[2][f] + L1[3][f];
        s2 = L2[0][f] + L2[1][f] + L2[2][f] + L2[3][f];
        int cnt = s1 - s0;
        float inv = (cnt > 0) ? 1.0f / (float)cnt : 0.f;
        float m = s * inv;
        float a = mscale[f];
        float var = s2 * inv - (2.f * a - a * a) * m * m;
        amean[g * DIM + f] = a * m;
        rstd[g * DIM + f] = rsqrtf(var + EPSV);
    }
}

// norm + ELU + residual; writes fp32 x (output) and bf16 copy for next GEMM
__global__ void k_norm(const float* __restrict__ A, const int* __restrict__ batch,
                       const float* __restrict__ amean, const float* __restrict__ rstd,
                       const float* __restrict__ gw, const float* __restrict__ gb,
                       const float* __restrict__ res, float* __restrict__ xout,
                       uint32_t* __restrict__ xb) {
    int i = blockIdx.x * blockDim.x + threadIdx.x;  // over N*32 float4 groups
    if (i >= N_NODES * 32) return;
    int n = i >> 5, q = i & 31;
    int g = batch[n];
    float4 v = ((const float4*)A)[i];
    float4 am = ((const float4*)amean)[g * 32 + q];
    float4 rs = ((const float4*)rstd)[g * 32 + q];
    float4 w = ((const float4*)gw)[q];
    float4 b = ((const float4*)gb)[q];
    float4 r = ((const float4*)res)[i];
    float4 o;
    o.x = w.x * (v.x - am.x) * rs.x + b.x;
    o.y = w.y * (v.y - am.y) * rs.y + b.y;
    o.z = w.z * (v.z - am.z) * rs.z + b.z;
    o.w = w.w * (v.w - am.w) * rs.w + b.w;
    o.x = ((o.x > 0.f) ? o.x : expm1f(o.x)) + r.x;
    o.y = ((o.y > 0.f) ? o.y : expm1f(o.y)) + r.y;
    o.z = ((o.z > 0.f) ? o.z : expm1f(o.z)) + r.z;
    o.w = ((o.w > 0.f) ? o.w : expm1f(o.w)) + r.w;
    ((float4*)xout)[i] = o;
    uint2 p;
    p.x = pack_bf2(o.x, o.y);
    p.y = pack_bf2(o.z, o.w);
    ((uint2*)xb)[i] = p;
}

__global__ void k_zero(float* __restrict__ p, int n) {
    int i = blockIdx.x * blockDim.x + threadIdx.x;
    if (i < n) p[i] = 0.f;
}

__global__ __launch_bounds__(128) void k_pool_partial(const float* __restrict__ X, const int* __restrict__ gstart,
                                                      float* __restrict__ pooled) {
    int g = blockIdx.x / NCHUNK;
    int c = blockIdx.x % NCHUNK;
    int s0 = gstart[g], s1 = gstart[g + 1];
    int len = s1 - s0;
    int a = s0 + (int)((long)len * c / NCHUNK);
    int b = s0 + (int)((long)len * (c + 1) / NCHUNK);
    int f = threadIdx.x;
    float s = 0.f;
    for (int n = a; n < b; ++n) s += X[(size_t)n * DIM + f];
    if (b > a) atomicAdd(&pooled[g * DIM + f], s);
}

__global__ __launch_bounds__(128) void k_head(const float* __restrict__ pooled,
                                              const float* __restrict__ w1, const float* __restrict__ b1,
                                              const float* __restrict__ gamma, const float* __restrict__ beta,
                                              const float* __restrict__ rmean, const float* __restrict__ rvar,
                                              const float* __restrict__ w2, const float* __restrict__ b2,
                                              float* __restrict__ zout) {
    __shared__ float sp[DIM];
    __shared__ float sz[DIM];
    int g = blockIdx.x, t = threadIdx.x;
    sp[t] = pooled[g * DIM + t];
    __syncthreads();
    float acc = b1[t];
#pragma unroll 8
    for (int k = 0; k < DIM; k++) acc += sp[k] * w1[k * DIM + t];
    acc = gamma[t] * (acc - rmean[t]) * rsqrtf(rvar[t] + EPSV) + beta[t];
    acc = fmaxf(acc, 0.f);
    sz[t] = acc;
    __syncthreads();
    if (t < NCLS) {
        float a2 = b2[t];
#pragma unroll 8
        for (int k = 0; k < DIM; k++) a2 += sz[k] * w2[k * NCLS + t];
        zout[g * NCLS + t] = a2;
    }
}

// ---------------- launch ----------------

extern "C" void kernel_launch(void* const* d_in, const int* in_sizes, int n_in,
                              void* d_out, int out_size, void* d_ws, size_t ws_size,
                              hipStream_t stream) {
    const float* x_in   = (const float*)d_in[0];
    const int*   ei     = (const int*)d_in[1];
    const int*   batch  = (const int*)d_in[2];
    const float* conv_w = (const float*)d_in[3];
    const float* conv_b = (const float*)d_in[4];
    const float* gn_w   = (const float*)d_in[5];
    const float* gn_b   = (const float*)d_in[6];
    const float* gn_ms  = (const float*)d_in[7];
    const float* w1     = (const float*)d_in[8];
    const float* b1     = (const float*)d_in[9];
    const float* bng    = (const float*)d_in[10];
    const float* bnb    = (const float*)d_in[11];
    const float* bnm    = (const float*)d_in[12];
    const float* bnv    = (const float*)d_in[13];
    const float* w2     = (const float*)d_in[14];
    const float* b2     = (const float*)d_in[15];

    float* out_x = (float*)d_out;
    float* out_z = out_x + (size_t)N_NODES * DIM;

    char* ws = (char*)d_ws;
    size_t off = 0;
    auto alloc = [&](size_t bytes) -> void* {
        void* p = ws + off;
        off += (bytes + 255) / 256 * 256;
        return p;
    };
    uint32_t* h      = (uint32_t*)alloc(sizeof(uint32_t) * (size_t)N_PAD * 64);   // bf16 H (padded)
    uint32_t* xb     = (uint32_t*)alloc(sizeof(uint32_t) * (size_t)N_PAD * 64);   // bf16 X (padded)
    float* agg       = (float*)alloc(sizeof(float) * (size_t)N_NODES * DIM);
    int*   csc_src   = (int*)alloc(sizeof(int) * (size_t)N_EDGES);
    float* csc_w     = (float*)alloc(sizeof(float) * (size_t)N_EDGES);
    uint32_t* wt     = (uint32_t*)alloc(sizeof(uint32_t) * NLAYERS * DIM * 64);   // bf16 W^T
    int*   deg       = (int*)alloc(sizeof(int) * N_NODES);
    float* dis       = (float*)alloc(sizeof(float) * N_NODES);
    int*   cursor    = (int*)alloc(sizeof(int) * N_NODES);
    int*   rowoff    = (int*)alloc(sizeof(int) * (N_NODES + 1));
    int*   bsum      = (int*)alloc(sizeof(int) * SCAN_NB);
    int*   boff      = (int*)alloc(sizeof(int) * SCAN_NB);
    int*   gstart    = (int*)alloc(sizeof(int) * (NGRAPH + 1));
    float* amean     = (float*)alloc(sizeof(float) * NGRAPH * DIM);
    float* rstd      = (float*)alloc(sizeof(float) * NGRAPH * DIM);
    float* pooled    = (float*)alloc(sizeof(float) * NGRAPH * DIM);

    // ---- prepass ----
    k_init<<<(N_NODES + 255) / 256, 256, 0, stream>>>(deg, cursor);
    k_edge_deg<<<(N_EDGES + 255) / 256, 256, 0, stream>>>(ei, deg);
    k_node_dis<<<(N_NODES + 255) / 256, 256, 0, stream>>>(deg, dis);
    k_gbound<<<(N_NODES + 255) / 256, 256, 0, stream>>>(batch, gstart);
    k_scan_bsum<<<SCAN_NB, SCAN_B, 0, stream>>>(deg, bsum);
    k_scan_mid<<<1, 256, 0, stream>>>(bsum, boff);
    k_scan_final<<<SCAN_NB, SCAN_B, 0, stream>>>(deg, boff, rowoff);
    k_build_csc<<<(N_EDGES + 255) / 256, 256, 0, stream>>>(ei, dis, rowoff, cursor, csc_src, csc_w);
    k_cast_w<<<(NLAYERS * DIM * 64 + 255) / 256, 256, 0, stream>>>(conv_w, wt);
    k_cast_x<<<(N_NODES * 64 + 255) / 256, 256, 0, stream>>>(x_in, xb);

    // ---- layers ----
    const float* xcur = x_in;
    for (int l = 0; l < NLAYERS; l++) {
        k_gemm_mfma<<<N_PAD / 64, 256, 0, stream>>>(xb, wt + (size_t)l * DIM * 64, h);
        k_aggregate<<<N_NODES / 4, 256, 0, stream>>>(h, csc_src, csc_w, rowoff, dis, conv_b + (size_t)l * DIM, agg);
        k_stats<<<NGRAPH, 512, 0, stream>>>(agg, gstart, gn_ms + (size_t)l * DIM, amean, rstd);
        k_norm<<<(N_NODES * 32 + 255) / 256, 256, 0, stream>>>(agg, batch, amean, rstd, gn_w + (size_t)l * DIM,
                                                               gn_b + (size_t)l * DIM, xcur, out_x, xb);
        xcur = out_x;
    }

    // ---- pool + head ----
    k_zero<<<(NGRAPH * DIM + 255) / 256, 256, 0, stream>>>(pooled, NGRAPH * DIM);
    k_pool_partial<<<NGRAPH * NCHUNK, 128, 0, stream>>>(out_x, gstart, pooled);
    k_head<<<NGRAPH, DIM, 0, stream>>>(pooled, w1, b1, bng, bnb, bnm, bnv, w2, b2, out_z);
}

// Round 5
// 1074.818 us; speedup vs baseline: 1.4132x; 1.0001x over previous
//
#include <hip/hip_runtime.h>
#include <stdint.h>

#define N_NODES 100000
#define N_PAD   100032            // 1563 * 64, padded rows for MFMA GEMM
#define N_EDGES 1600000
#define DIM 128
#define NLAYERS 4
#define NGRAPH 128
#define NCLS 10
#define EPSV 1e-5f

#define SCAN_B 512
#define SCAN_NB ((N_NODES + SCAN_B - 1) / SCAN_B)   // 196

typedef __attribute__((ext_vector_type(8))) short short8_t;   // 8 bf16
typedef __attribute__((ext_vector_type(4))) float float4_t;   // 4 fp32 acc

// ---------------- bf16 helpers ----------------

__device__ __forceinline__ float bf_lo(uint32_t u) { return __uint_as_float(u << 16); }
__device__ __forceinline__ float bf_hi(uint32_t u) { return __uint_as_float(u & 0xffff0000u); }
__device__ __forceinline__ uint32_t f2bf_rne(float f) {
    uint32_t x = __float_as_uint(f);
    return (x + 0x7fffu + ((x >> 16) & 1u)) >> 16;
}
__device__ __forceinline__ uint32_t pack_bf2(float a, float b) {
    return f2bf_rne(a) | (f2bf_rne(b) << 16);
}

// ---------------- prepass kernels ----------------

__global__ void k_init(int* __restrict__ deg, int* __restrict__ cursor) {
    int i = blockIdx.x * blockDim.x + threadIdx.x;
    if (i < N_NODES) { deg[i] = 1; cursor[i] = 0; }
}

__global__ void k_edge_deg(const int* __restrict__ ei, int* __restrict__ deg) {
    int e = blockIdx.x * blockDim.x + threadIdx.x;
    if (e < N_EDGES) atomicAdd(&deg[ei[N_EDGES + e]], 1);
}

// fused: dis = rsqrt(deg); graph boundaries from SORTED batch (no atomics)
__global__ void k_node_meta(const int* __restrict__ deg, float* __restrict__ dis,
                            const int* __restrict__ batch, int* __restrict__ gstart) {
    int i = blockIdx.x * blockDim.x + threadIdx.x;
    if (i >= N_NODES) return;
    dis[i] = rsqrtf((float)deg[i]);
    int b = batch[i];
    if (i == 0) {
        for (int g = 0; g <= b; g++) gstart[g] = 0;
    } else {
        int bp = batch[i - 1];
        for (int g = bp + 1; g <= b; g++) gstart[g] = i;
    }
    if (i == N_NODES - 1) {
        for (int g = b + 1; g <= NGRAPH; g++) gstart[g] = N_NODES;
    }
}

__global__ __launch_bounds__(SCAN_B) void k_scan_bsum(const int* __restrict__ deg, int* __restrict__ bsum) {
    __shared__ int s[SCAN_B];
    int t = threadIdx.x;
    int n = blockIdx.x * SCAN_B + t;
    int v = (n < N_NODES) ? deg[n] - 1 : 0;
    s[t] = v; __syncthreads();
    for (int off = SCAN_B / 2; off > 0; off >>= 1) {
        if (t < off) s[t] += s[t + off];
        __syncthreads();
    }
    if (t == 0) bsum[blockIdx.x] = s[0];
}

__global__ __launch_bounds__(256) void k_scan_mid(const int* __restrict__ bsum, int* __restrict__ boff) {
    __shared__ int s[256];
    int t = threadIdx.x;
    int v = (t < SCAN_NB) ? bsum[t] : 0;
    s[t] = v; __syncthreads();
    for (int off = 1; off < 256; off <<= 1) {
        int a = (t >= off) ? s[t - off] : 0;
        __syncthreads();
        s[t] += a;
        __syncthreads();
    }
    if (t < SCAN_NB) boff[t] = s[t] - v;
}

__global__ __launch_bounds__(SCAN_B) void k_scan_final(const int* __restrict__ deg, const int* __restrict__ boff,
                                                       int* __restrict__ rowoff) {
    __shared__ int s[SCAN_B];
    int t = threadIdx.x;
    int n = blockIdx.x * SCAN_B + t;
    int v = (n < N_NODES) ? deg[n] - 1 : 0;
    s[t] = v; __syncthreads();
    for (int off = 1; off < SCAN_B; off <<= 1) {
        int a = (t >= off) ? s[t - off] : 0;
        __syncthreads();
        s[t] += a;
        __syncthreads();
    }
    int excl = s[t] - v;
    if (n <= N_NODES) rowoff[n] = boff[blockIdx.x] + excl;
}

// merged CSC entry: .x = src node, .y = edge weight (float bits) -> ONE 8B scatter/edge
__global__ void k_build_csc(const int* __restrict__ ei, const float* __restrict__ dis,
                            const int* __restrict__ rowoff, int* __restrict__ cursor,
                            int2* __restrict__ csc) {
    int e = blockIdx.x * blockDim.x + threadIdx.x;
    if (e >= N_EDGES) return;
    int s = ei[e];
    int d = ei[N_EDGES + e];
    int pos = rowoff[d] + atomicAdd(&cursor[d], 1);
    csc[pos] = make_int2(s, __float_as_int(dis[s] * dis[d]));
}

// cast conv_w (fp32, [L][K][N]) -> Wt (bf16, [L][N][K] packed as uint pairs along K)
__global__ void k_cast_w(const float* __restrict__ W, uint32_t* __restrict__ Wt) {
    int i = blockIdx.x * blockDim.x + threadIdx.x;    // over L*128*64
    if (i >= NLAYERS * DIM * 64) return;
    int l = i / (DIM * 64);
    int n = (i / 64) % DIM;
    int ku = i % 64;
    const float* Wl = W + (size_t)l * DIM * DIM;
    float w0 = Wl[(2 * ku) * DIM + n];
    float w1 = Wl[(2 * ku + 1) * DIM + n];
    Wt[i] = pack_bf2(w0, w1);
}

// cast x (fp32 [N][128]) -> Xb (bf16, uint pairs)
__global__ void k_cast_x(const float* __restrict__ X, uint32_t* __restrict__ Xb) {
    int i = blockIdx.x * blockDim.x + threadIdx.x;    // over N*64
    if (i >= N_NODES * 64) return;
    float2 v = ((const float2*)X)[i];
    Xb[i] = pack_bf2(v.x, v.y);
}

// ---------------- per-layer kernels ----------------

// H[64 rows][128] bf16 = Xb @ Wt via mfma_f32_16x16x32_bf16.
__global__ __launch_bounds__(256) void k_gemm_mfma(const uint32_t* __restrict__ Xb,
                                                   const uint32_t* __restrict__ Wt,
                                                   uint32_t* __restrict__ H) {
    __shared__ float tile[64][132];
    int t = threadIdx.x;
    int wid = t >> 6;
    int lane = t & 63;
    int quad = lane >> 4;
    int s15 = lane & 15;
    size_t row_base = (size_t)blockIdx.x * 64 + wid * 16;

    float4_t acc[8];
#pragma unroll
    for (int i = 0; i < 8; i++) acc[i] = (float4_t){0.f, 0.f, 0.f, 0.f};

    const uint32_t* arow = Xb + (row_base + s15) * 64 + quad * 4;
#pragma unroll
    for (int kk = 0; kk < 4; kk++) {
        uint4 au = *(const uint4*)(arow + kk * 16);
        short8_t a = __builtin_bit_cast(short8_t, au);
#pragma unroll
        for (int nt = 0; nt < 8; nt++) {
            uint4 bu = *(const uint4*)(Wt + (size_t)(nt * 16 + s15) * 64 + kk * 16 + quad * 4);
            short8_t b = __builtin_bit_cast(short8_t, bu);
            acc[nt] = __builtin_amdgcn_mfma_f32_16x16x32_bf16(a, b, acc[nt], 0, 0, 0);
        }
    }
    // C layout: col = lane&15, row = quad*4 + reg
#pragma unroll
    for (int nt = 0; nt < 8; nt++) {
#pragma unroll
        for (int r = 0; r < 4; r++) {
            tile[wid * 16 + quad * 4 + r][nt * 16 + s15] = acc[nt][r];
        }
    }
    __syncthreads();
    uint32_t* Hb = H + (size_t)blockIdx.x * 64 * 64;
#pragma unroll
    for (int i = 0; i < 16; i++) {
        int idx = t + 256 * i;            // over 4096 uints
        int row = idx >> 6, cu = idx & 63;
        float2 v = *(const float2*)&tile[row][cu * 2];
        Hb[(size_t)row * 64 + cu] = pack_bf2(v.x, v.y);
    }
}

// pull aggregation: 1 wave per node, quarter-wave rows, merged int2 edge entries.
__global__ __launch_bounds__(256) void k_aggregate(const uint32_t* __restrict__ H,
                                                   const int2* __restrict__ csc,
                                                   const int* __restrict__ rowoff,
                                                   const float* __restrict__ dis,
                                                   const float* __restrict__ bias,
                                                   float* __restrict__ Out) {
    int wid = threadIdx.x >> 6;
    int lane = threadIdx.x & 63;
    int q = lane >> 4;
    int s = lane & 15;
    int n = blockIdx.x * 4 + wid;     // grid = N/4 exactly

    float acc[8];
    {
        float d = dis[n];
        float sw = (q == 0) ? d * d : 0.f;     // self term counted once (quad 0)
        uint4 us = ((const uint4*)(H + (size_t)n * 64))[s];
        acc[0] = sw * bf_lo(us.x); acc[1] = sw * bf_hi(us.x);
        acc[2] = sw * bf_lo(us.y); acc[3] = sw * bf_hi(us.y);
        acc[4] = sw * bf_lo(us.z); acc[5] = sw * bf_hi(us.z);
        acc[6] = sw * bf_lo(us.w); acc[7] = sw * bf_hi(us.w);
    }

    int b0 = rowoff[n], b1 = rowoff[n + 1];
    for (int j = b0; j < b1; j += 8) {
        int e0 = j + q;
        int e1 = j + 4 + q;
        int2 c0 = csc[(e0 < b1) ? e0 : b0];
        int2 c1 = csc[(e1 < b1) ? e1 : b0];
        float w0 = (e0 < b1) ? __int_as_float(c0.y) : 0.f;
        float w1 = (e1 < b1) ? __int_as_float(c1.y) : 0.f;
        uint4 u0 = ((const uint4*)(H + (size_t)c0.x * 64))[s];
        uint4 u1 = ((const uint4*)(H + (size_t)c1.x * 64))[s];
        acc[0] += w0 * bf_lo(u0.x); acc[1] += w0 * bf_hi(u0.x);
        acc[2] += w0 * bf_lo(u0.y); acc[3] += w0 * bf_hi(u0.y);
        acc[4] += w0 * bf_lo(u0.z); acc[5] += w0 * bf_hi(u0.z);
        acc[6] += w0 * bf_lo(u0.w); acc[7] += w0 * bf_hi(u0.w);
        acc[0] += w1 * bf_lo(u1.x); acc[1] += w1 * bf_hi(u1.x);
        acc[2] += w1 * bf_lo(u1.y); acc[3] += w1 * bf_hi(u1.y);
        acc[4] += w1 * bf_lo(u1.z); acc[5] += w1 * bf_hi(u1.z);
        acc[6] += w1 * bf_lo(u1.w); acc[7] += w1 * bf_hi(u1.w);
    }
    // combine quarters
#pragma unroll
    for (int k = 0; k < 8; k++) {
        acc[k] += __shfl_xor(acc[k], 16);
        acc[k] += __shfl_xor(acc[k], 32);
    }
    // lane (q,s) writes features s*8 + 2q, s*8 + 2q + 1  -> fully coalesced 512B
    float o0 = (q == 0) ? acc[0] : (q == 1) ? acc[2] : (q == 2) ? acc[4] : acc[6];
    float o1 = (q == 0) ? acc[1] : (q == 1) ? acc[3] : (q == 2) ? acc[5] : acc[7];
    float2 bb = ((const float2*)bias)[s * 4 + q];
    ((float2*)(Out + (size_t)n * DIM))[s * 4 + q] = make_float2(o0 + bb.x, o1 + bb.y);
}

// GraphNorm stats: one block per graph, 512 thr (4 row-parts x 128 features)
__global__ __launch_bounds__(512) void k_stats(const float* __restrict__ A, const int* __restrict__ gstart,
                                               const float* __restrict__ mscale,
                                               float* __restrict__ amean, float* __restrict__ rstd) {
    __shared__ float L1[4][DIM];
    __shared__ float L2[4][DIM];
    int g = blockIdx.x;
    int t = threadIdx.x;
    int f = t & 127;
    int p = t >> 7;
    int s0 = gstart[g], s1 = gstart[g + 1];
    float s = 0.f, s2 = 0.f;
    for (int n = s0 + p; n < s1; n += 4) {
        float v = A[(size_t)n * DIM + f];
        s += v;
        s2 += v * v;
    }
    L1[p][f] = s; L2[p][f] = s2;
    __syncthreads();
    if (p == 0) {
        s = L1[0][f] + L1[1][f] + L1[2][f] + L1[3][f];
        s2 = L2[0][f] + L2[1][f] + L2[2][f] + L2[3][f];
        int cnt = s1 - s0;
        float inv = (cnt > 0) ? 1.0f / (float)cnt : 0.f;
        float m = s * inv;
        float a = mscale[f];
        float var = s2 * inv - (2.f * a - a * a) * m * m;
        amean[g * DIM + f] = a * m;
        rstd[g * DIM + f] = rsqrtf(var + EPSV);
    }
}

// norm + ELU + residual; writes fp32 x (output) and bf16 copy for next GEMM
__global__ void k_norm(const float* __restrict__ A, const int* __restrict__ batch,
                       const float* __restrict__ amean, const float* __restrict__ rstd,
                       const float* __restrict__ gw, const float* __restrict__ gb,
                       const float* __restrict__ res, float* __restrict__ xout,
                       uint32_t* __restrict__ xb) {
    int i = blockIdx.x * blockDim.x + threadIdx.x;  // over N*32 float4 groups
    if (i >= N_NODES * 32) return;
    int n = i >> 5, q = i & 31;
    int g = batch[n];
    float4 v = ((const float4*)A)[i];
    float4 am = ((const float4*)amean)[g * 32 + q];
    float4 rs = ((const float4*)rstd)[g * 32 + q];
    float4 w = ((const float4*)gw)[q];
    float4 b = ((const float4*)gb)[q];
    float4 r = ((const float4*)res)[i];
    float4 o;
    o.x = w.x * (v.x - am.x) * rs.x + b.x;
    o.y = w.y * (v.y - am.y) * rs.y + b.y;
    o.z = w.z * (v.z - am.z) * rs.z + b.z;
    o.w = w.w * (v.w - am.w) * rs.w + b.w;
    o.x = ((o.x > 0.f) ? o.x : expm1f(o.x)) + r.x;
    o.y = ((o.y > 0.f) ? o.y : expm1f(o.y)) + r.y;
    o.z = ((o.z > 0.f) ? o.z : expm1f(o.z)) + r.z;
    o.w = ((o.w > 0.f) ? o.w : expm1f(o.w)) + r.w;
    ((float4*)xout)[i] = o;
    uint2 p;
    p.x = pack_bf2(o.x, o.y);
    p.y = pack_bf2(o.z, o.w);
    ((uint2*)xb)[i] = p;
}

// fused global_add_pool + dense head: one block per graph, 512 thr
__global__ __launch_bounds__(512) void k_pool_head(const float* __restrict__ X, const int* __restrict__ gstart,
                                                   const float* __restrict__ w1, const float* __restrict__ b1,
                                                   const float* __restrict__ gamma, const float* __restrict__ beta,
                                                   const float* __restrict__ rmean, const float* __restrict__ rvar,
                                                   const float* __restrict__ w2, const float* __restrict__ b2,
                                                   float* __restrict__ zout) {
    __shared__ float L[4][DIM];
    __shared__ float sp[DIM];
    __shared__ float sz[DIM];
    int g = blockIdx.x, t = threadIdx.x;
    int f = t & 127;
    int p = t >> 7;
    int s0 = gstart[g], s1 = gstart[g + 1];
    float s = 0.f;
    for (int n = s0 + p; n < s1; n += 4) s += X[(size_t)n * DIM + f];
    L[p][f] = s;
    __syncthreads();
    if (p == 0) sp[f] = L[0][f] + L[1][f] + L[2][f] + L[3][f];
    __syncthreads();
    if (p == 0) {
        float acc = b1[f];
#pragma unroll 8
        for (int k = 0; k < DIM; k++) acc += sp[k] * w1[k * DIM + f];
        acc = gamma[f] * (acc - rmean[f]) * rsqrtf(rvar[f] + EPSV) + beta[f];
        sz[f] = fmaxf(acc, 0.f);
    }
    __syncthreads();
    if (t < NCLS) {
        float a2 = b2[t];
#pragma unroll 8
        for (int k = 0; k < DIM; k++) a2 += sz[k] * w2[k * NCLS + t];
        zout[g * NCLS + t] = a2;
    }
}

// ---------------- launch ----------------

extern "C" void kernel_launch(void* const* d_in, const int* in_sizes, int n_in,
                              void* d_out, int out_size, void* d_ws, size_t ws_size,
                              hipStream_t stream) {
    const float* x_in   = (const float*)d_in[0];
    const int*   ei     = (const int*)d_in[1];
    const int*   batch  = (const int*)d_in[2];
    const float* conv_w = (const float*)d_in[3];
    const float* conv_b = (const float*)d_in[4];
    const float* gn_w   = (const float*)d_in[5];
    const float* gn_b   = (const float*)d_in[6];
    const float* gn_ms  = (const float*)d_in[7];
    const float* w1     = (const float*)d_in[8];
    const float* b1     = (const float*)d_in[9];
    const float* bng    = (const float*)d_in[10];
    const float* bnb    = (const float*)d_in[11];
    const float* bnm    = (const float*)d_in[12];
    const float* bnv    = (const float*)d_in[13];
    const float* w2     = (const float*)d_in[14];
    const float* b2     = (const float*)d_in[15];

    float* out_x = (float*)d_out;
    float* out_z = out_x + (size_t)N_NODES * DIM;

    char* ws = (char*)d_ws;
    size_t off = 0;
    auto alloc = [&](size_t bytes) -> void* {
        void* p = ws + off;
        off += (bytes + 255) / 256 * 256;
        return p;
    };
    uint32_t* h      = (uint32_t*)alloc(sizeof(uint32_t) * (size_t)N_PAD * 64);   // bf16 H (padded)
    uint32_t* xb     = (uint32_t*)alloc(sizeof(uint32_t) * (size_t)N_PAD * 64);   // bf16 X (padded)
    float* agg       = (float*)alloc(sizeof(float) * (size_t)N_NODES * DIM);
    int2*  csc       = (int2*)alloc(sizeof(int2) * (size_t)N_EDGES);              // merged (src, w)
    uint32_t* wt     = (uint32_t*)alloc(sizeof(uint32_t) * NLAYERS * DIM * 64);   // bf16 W^T
    int*   deg       = (int*)alloc(sizeof(int) * N_NODES);
    float* dis       = (float*)alloc(sizeof(float) * N_NODES);
    int*   cursor    = (int*)alloc(sizeof(int) * N_NODES);
    int*   rowoff    = (int*)alloc(sizeof(int) * (N_NODES + 1));
    int*   bsum      = (int*)alloc(sizeof(int) * SCAN_NB);
    int*   boff      = (int*)alloc(sizeof(int) * SCAN_NB);
    int*   gstart    = (int*)alloc(sizeof(int) * (NGRAPH + 1));
    float* amean     = (float*)alloc(sizeof(float) * NGRAPH * DIM);
    float* rstd      = (float*)alloc(sizeof(float) * NGRAPH * DIM);

    // ---- prepass ----
    k_init<<<(N_NODES + 255) / 256, 256, 0, stream>>>(deg, cursor);
    k_edge_deg<<<(N_EDGES + 255) / 256, 256, 0, stream>>>(ei, deg);
    k_node_meta<<<(N_NODES + 255) / 256, 256, 0, stream>>>(deg, dis, batch, gstart);
    k_scan_bsum<<<SCAN_NB, SCAN_B, 0, stream>>>(deg, bsum);
    k_scan_mid<<<1, 256, 0, stream>>>(bsum, boff);
    k_scan_final<<<SCAN_NB, SCAN_B, 0, stream>>>(deg, boff, rowoff);
    k_build_csc<<<(N_EDGES + 255) / 256, 256, 0, stream>>>(ei, dis, rowoff, cursor, csc);
    k_cast_w<<<(NLAYERS * DIM * 64 + 255) / 256, 256, 0, stream>>>(conv_w, wt);
    k_cast_x<<<(N_NODES * 64 + 255) / 256, 256, 0, stream>>>(x_in, xb);

    // ---- layers ----
    const float* xcur = x_in;
    for (int l = 0; l < NLAYERS; l++) {
        k_gemm_mfma<<<N_PAD / 64, 256, 0, stream>>>(xb, wt + (size_t)l * DIM * 64, h);
        k_aggregate<<<N_NODES / 4, 256, 0, stream>>>(h, csc, rowoff, dis, conv_b + (size_t)l * DIM, agg);
        k_stats<<<NGRAPH, 512, 0, stream>>>(agg, gstart, gn_ms + (size_t)l * DIM, amean, rstd);
        k_norm<<<(N_NODES * 32 + 255) / 256, 256, 0, stream>>>(agg, batch, amean, rstd, gn_w + (size_t)l * DIM,
                                                               gn_b + (size_t)l * DIM, xcur, out_x, xb);
        xcur = out_x;
    }

    // ---- pool + head ----
    k_pool_head<<<NGRAPH, 512, 0, stream>>>(out_x, gstart, w1, b1, bng, bnb, bnm, bnv, w2, b2, out_z);
}

// Round 6
// 1013.794 us; speedup vs baseline: 1.4983x; 1.0602x over previous
//
#include <hip/hip_runtime.h>
#include <stdint.h>

#define N_NODES 100000
#define N_PAD   100032            // 1563 * 64, padded rows for MFMA GEMM
#define N_EDGES 1600000
#define DIM 128
#define NLAYERS 4
#define NGRAPH 128
#define NCLS 10
#define EPSV 1e-5f

#define SCAN_B 512
#define SCAN_NB ((N_NODES + SCAN_B - 1) / SCAN_B)   // 196

#define BIN_SHIFT 9
#define NBUCKET ((N_NODES + 511) >> 9)              // 196
#define P1_EPB 4096
#define P1_BLOCKS ((N_EDGES + P1_EPB - 1) / P1_EPB) // 391

typedef __attribute__((ext_vector_type(8))) short short8_t;   // 8 bf16
typedef __attribute__((ext_vector_type(4))) float float4_t;   // 4 fp32 acc

// ---------------- bf16 helpers ----------------

__device__ __forceinline__ float bf_lo(uint32_t u) { return __uint_as_float(u << 16); }
__device__ __forceinline__ float bf_hi(uint32_t u) { return __uint_as_float(u & 0xffff0000u); }
__device__ __forceinline__ uint32_t f2bf_rne(float f) {
    uint32_t x = __float_as_uint(f);
    return (x + 0x7fffu + ((x >> 16) & 1u)) >> 16;
}
__device__ __forceinline__ uint32_t pack_bf2(float a, float b) {
    return f2bf_rne(a) | (f2bf_rne(b) << 16);
}

// ---------------- prepass kernels ----------------

__global__ void k_init(int* __restrict__ deg) {
    int i = blockIdx.x * blockDim.x + threadIdx.x;
    if (i < N_NODES) deg[i] = 1;
}

__global__ void k_edge_deg(const int* __restrict__ ei, int* __restrict__ deg) {
    int e = blockIdx.x * blockDim.x + threadIdx.x;
    if (e < N_EDGES) atomicAdd(&deg[ei[N_EDGES + e]], 1);
}

// fused: dis = rsqrt(deg); graph boundaries from SORTED batch (no atomics)
__global__ void k_node_meta(const int* __restrict__ deg, float* __restrict__ dis,
                            const int* __restrict__ batch, int* __restrict__ gstart) {
    int i = blockIdx.x * blockDim.x + threadIdx.x;
    if (i >= N_NODES) return;
    dis[i] = rsqrtf((float)deg[i]);
    int b = batch[i];
    if (i == 0) {
        for (int g = 0; g <= b; g++) gstart[g] = 0;
    } else {
        int bp = batch[i - 1];
        for (int g = bp + 1; g <= b; g++) gstart[g] = i;
    }
    if (i == N_NODES - 1) {
        for (int g = b + 1; g <= NGRAPH; g++) gstart[g] = N_NODES;
    }
}

__global__ __launch_bounds__(SCAN_B) void k_scan_bsum(const int* __restrict__ deg, int* __restrict__ bsum) {
    __shared__ int s[SCAN_B];
    int t = threadIdx.x;
    int n = blockIdx.x * SCAN_B + t;
    int v = (n < N_NODES) ? deg[n] - 1 : 0;
    s[t] = v; __syncthreads();
    for (int off = SCAN_B / 2; off > 0; off >>= 1) {
        if (t < off) s[t] += s[t + off];
        __syncthreads();
    }
    if (t == 0) bsum[blockIdx.x] = s[0];
}

__global__ __launch_bounds__(256) void k_scan_mid(const int* __restrict__ bsum, int* __restrict__ boff) {
    __shared__ int s[256];
    int t = threadIdx.x;
    int v = (t < SCAN_NB) ? bsum[t] : 0;
    s[t] = v; __syncthreads();
    for (int off = 1; off < 256; off <<= 1) {
        int a = (t >= off) ? s[t - off] : 0;
        __syncthreads();
        s[t] += a;
        __syncthreads();
    }
    if (t < SCAN_NB) boff[t] = s[t] - v;
}

__global__ __launch_bounds__(SCAN_B) void k_scan_final(const int* __restrict__ deg, const int* __restrict__ boff,
                                                       int* __restrict__ rowoff) {
    __shared__ int s[SCAN_B];
    int t = threadIdx.x;
    int n = blockIdx.x * SCAN_B + t;
    int v = (n < N_NODES) ? deg[n] - 1 : 0;
    s[t] = v; __syncthreads();
    for (int off = 1; off < SCAN_B; off <<= 1) {
        int a = (t >= off) ? s[t - off] : 0;
        __syncthreads();
        s[t] += a;
        __syncthreads();
    }
    int excl = s[t] - v;
    if (n <= N_NODES) rowoff[n] = boff[blockIdx.x] + excl;
}

// bucket cursors start at the bucket's final CSC offset
__global__ void k_bucket_init(const int* __restrict__ rowoff, int* __restrict__ bcur) {
    int b = threadIdx.x;
    if (b < NBUCKET) {
        int n0 = b << BIN_SHIFT;
        bcur[b] = rowoff[(n0 < N_NODES) ? n0 : N_NODES];
    }
}

// pass 1: bin edges by dst bucket (append-sequential writes per bucket)
__global__ __launch_bounds__(256) void k_bin_edges(const int* __restrict__ ei,
                                                   int* __restrict__ bcur,
                                                   int2* __restrict__ binned) {
    __shared__ int hist[NBUCKET];
    __shared__ int base[NBUCKET];
    int t = threadIdx.x;
    int e0 = blockIdx.x * P1_EPB;
    int e1 = e0 + P1_EPB; if (e1 > N_EDGES) e1 = N_EDGES;
    for (int i = t; i < NBUCKET; i += 256) hist[i] = 0;
    __syncthreads();
    int myrank[P1_EPB / 256];
    int cnt = 0;
    for (int e = e0 + t; e < e1; e += 256) {
        int d = ei[N_EDGES + e];
        myrank[cnt++] = atomicAdd(&hist[d >> BIN_SHIFT], 1);
    }
    __syncthreads();
    for (int i = t; i < NBUCKET; i += 256) base[i] = atomicAdd(&bcur[i], hist[i]);
    __syncthreads();
    cnt = 0;
    for (int e = e0 + t; e < e1; e += 256) {
        int s = ei[e];
        int d = ei[N_EDGES + e];
        binned[base[d >> BIN_SHIFT] + myrank[cnt++]] = make_int2(s, d);
    }
}

// pass 2: one block per bucket; scatter within the bucket's L2-resident window.
// per-dst rank via LDS counters (512 nodes per bucket).
__global__ __launch_bounds__(256) void k_scatter(const int2* __restrict__ binned,
                                                 const float* __restrict__ dis,
                                                 const int* __restrict__ rowoff,
                                                 int2* __restrict__ csc) {
    __shared__ int lcur[512];
    int b = blockIdx.x;
    int t = threadIdx.x;
    int n0 = b << BIN_SHIFT;
    int n1 = n0 + 512; if (n1 > N_NODES) n1 = N_NODES;
    lcur[t] = 0; lcur[t + 256] = 0;
    __syncthreads();
    int j0 = rowoff[n0], j1 = rowoff[n1];
    for (int j = j0 + t; j < j1; j += 256) {
        int2 sd = binned[j];
        float w = dis[sd.x] * dis[sd.y];
        int rank = atomicAdd(&lcur[sd.y & 511], 1);
        csc[rowoff[sd.y] + rank] = make_int2(sd.x, __float_as_int(w));
    }
}

// cast conv_w (fp32, [L][K][N]) -> Wt (bf16, [L][N][K] packed as uint pairs along K)
__global__ void k_cast_w(const float* __restrict__ W, uint32_t* __restrict__ Wt) {
    int i = blockIdx.x * blockDim.x + threadIdx.x;    // over L*128*64
    if (i >= NLAYERS * DIM * 64) return;
    int l = i / (DIM * 64);
    int n = (i / 64) % DIM;
    int ku = i % 64;
    const float* Wl = W + (size_t)l * DIM * DIM;
    float w0 = Wl[(2 * ku) * DIM + n];
    float w1 = Wl[(2 * ku + 1) * DIM + n];
    Wt[i] = pack_bf2(w0, w1);
}

// ---------------- GEMM cores (shared by gemm0 / norm_gemm) ----------------

// MFMA phase: A-tile in LDS (uint [64][68], bf16 pairs), B = Wt global, out H bf16.
__device__ __forceinline__ void gemm_phase(const uint32_t (*atile)[68], const uint32_t* __restrict__ Wt,
                                           float (*ctile)[132], uint32_t* __restrict__ H,
                                           int blk, int t) {
    int wid = t >> 6;
    int lane = t & 63;
    int quad = lane >> 4;
    int s15 = lane & 15;

    float4_t acc[8];
#pragma unroll
    for (int i = 0; i < 8; i++) acc[i] = (float4_t){0.f, 0.f, 0.f, 0.f};

#pragma unroll
    for (int kk = 0; kk < 4; kk++) {
        uint4 au = *(const uint4*)&atile[wid * 16 + s15][quad * 4 + kk * 16];
        short8_t a = __builtin_bit_cast(short8_t, au);
#pragma unroll
        for (int nt = 0; nt < 8; nt++) {
            uint4 bu = *(const uint4*)(Wt + (size_t)(nt * 16 + s15) * 64 + kk * 16 + quad * 4);
            short8_t b = __builtin_bit_cast(short8_t, bu);
            acc[nt] = __builtin_amdgcn_mfma_f32_16x16x32_bf16(a, b, acc[nt], 0, 0, 0);
        }
    }
    __syncthreads();       // A-tile dead; reuse LDS for C
#pragma unroll
    for (int nt = 0; nt < 8; nt++) {
#pragma unroll
        for (int r = 0; r < 4; r++) {
            ctile[wid * 16 + quad * 4 + r][nt * 16 + s15] = acc[nt][r];
        }
    }
    __syncthreads();
    uint32_t* Hb = H + (size_t)blk * 64 * 64;
#pragma unroll
    for (int i = 0; i < 16; i++) {
        int idx = t + 256 * i;            // over 4096 uints
        int row = idx >> 6, cu = idx & 63;
        float2 v = *(const float2*)&ctile[row][cu * 2];
        Hb[(size_t)row * 64 + cu] = pack_bf2(v.x, v.y);
    }
}

// layer-0 GEMM: cast x_in (fp32) to bf16 A-tile in LDS, then MFMA
__global__ __launch_bounds__(256) void k_gemm0(const float* __restrict__ X, const uint32_t* __restrict__ Wt,
                                               uint32_t* __restrict__ H) {
    __shared__ __align__(16) char smem[64 * 132 * 4];
    uint32_t (*atile)[68] = (uint32_t(*)[68])smem;
    float (*ctile)[132] = (float(*)[132])smem;
    int t = threadIdx.x;
    size_t row0 = (size_t)blockIdx.x * 64;
#pragma unroll
    for (int i = 0; i < 8; i++) {
        int idx = t + 256 * i;            // 2048 float4-groups
        int row = idx >> 5, q = idx & 31;
        size_t gr = row0 + row;
        uint2 p = make_uint2(0u, 0u);
        if (gr < N_NODES) {
            float4 v = ((const float4*)(X + gr * DIM))[q];
            p.x = pack_bf2(v.x, v.y);
            p.y = pack_bf2(v.z, v.w);
        }
        *(uint2*)&atile[row][q * 2] = p;
    }
    __syncthreads();
    gemm_phase(atile, Wt, ctile, H, blockIdx.x, t);
}

// fused GraphNorm+ELU+residual (layer l) + GEMM (layer l+1)
__global__ __launch_bounds__(256) void k_norm_gemm(const float* __restrict__ A, const int* __restrict__ batch,
                                                   const float* __restrict__ amean, const float* __restrict__ rstd,
                                                   const float* __restrict__ gw, const float* __restrict__ gb,
                                                   const float* __restrict__ res, float* __restrict__ xout,
                                                   const uint32_t* __restrict__ Wt, uint32_t* __restrict__ H) {
    __shared__ __align__(16) char smem[64 * 132 * 4];
    uint32_t (*atile)[68] = (uint32_t(*)[68])smem;
    float (*ctile)[132] = (float(*)[132])smem;
    int t = threadIdx.x;
    size_t row0 = (size_t)blockIdx.x * 64;
#pragma unroll
    for (int i = 0; i < 8; i++) {
        int idx = t + 256 * i;            // 2048 float4-groups
        int row = idx >> 5, q = idx & 31;
        size_t gr = row0 + row;
        uint2 p = make_uint2(0u, 0u);
        if (gr < N_NODES) {
            int g = batch[gr];
            size_t gi = gr * 32 + q;
            float4 v = ((const float4*)A)[gi];
            float4 am = ((const float4*)amean)[g * 32 + q];
            float4 rs = ((const float4*)rstd)[g * 32 + q];
            float4 w = ((const float4*)gw)[q];
            float4 b = ((const float4*)gb)[q];
            float4 r = ((const float4*)res)[gi];
            float4 o;
            o.x = w.x * (v.x - am.x) * rs.x + b.x;
            o.y = w.y * (v.y - am.y) * rs.y + b.y;
            o.z = w.z * (v.z - am.z) * rs.z + b.z;
            o.w = w.w * (v.w - am.w) * rs.w + b.w;
            o.x = ((o.x > 0.f) ? o.x : expm1f(o.x)) + r.x;
            o.y = ((o.y > 0.f) ? o.y : expm1f(o.y)) + r.y;
            o.z = ((o.z > 0.f) ? o.z : expm1f(o.z)) + r.z;
            o.w = ((o.w > 0.f) ? o.w : expm1f(o.w)) + r.w;
            ((float4*)xout)[gi] = o;
            p.x = pack_bf2(o.x, o.y);
            p.y = pack_bf2(o.z, o.w);
        }
        *(uint2*)&atile[row][q * 2] = p;
    }
    __syncthreads();
    gemm_phase(atile, Wt, ctile, H, blockIdx.x, t);
}

// ---------------- per-layer kernels ----------------

// pull aggregation: 1 wave per node, quarter-wave rows, merged int2 edge entries.
__global__ __launch_bounds__(256) void k_aggregate(const uint32_t* __restrict__ H,
                                                   const int2* __restrict__ csc,
                                                   const int* __restrict__ rowoff,
                                                   const float* __restrict__ dis,
                                                   const float* __restrict__ bias,
                                                   float* __restrict__ Out) {
    int wid = threadIdx.x >> 6;
    int lane = threadIdx.x & 63;
    int q = lane >> 4;
    int s = lane & 15;
    int n = blockIdx.x * 4 + wid;     // grid = N/4 exactly

    float acc[8];
    {
        float d = dis[n];
        float sw = (q == 0) ? d * d : 0.f;     // self term counted once (quad 0)
        uint4 us = ((const uint4*)(H + (size_t)n * 64))[s];
        acc[0] = sw * bf_lo(us.x); acc[1] = sw * bf_hi(us.x);
        acc[2] = sw * bf_lo(us.y); acc[3] = sw * bf_hi(us.y);
        acc[4] = sw * bf_lo(us.z); acc[5] = sw * bf_hi(us.z);
        acc[6] = sw * bf_lo(us.w); acc[7] = sw * bf_hi(us.w);
    }

    int b0 = rowoff[n], b1 = rowoff[n + 1];
    for (int j = b0; j < b1; j += 8) {
        int e0 = j + q;
        int e1 = j + 4 + q;
        int2 c0 = csc[(e0 < b1) ? e0 : b0];
        int2 c1 = csc[(e1 < b1) ? e1 : b0];
        float w0 = (e0 < b1) ? __int_as_float(c0.y) : 0.f;
        float w1 = (e1 < b1) ? __int_as_float(c1.y) : 0.f;
        uint4 u0 = ((const uint4*)(H + (size_t)c0.x * 64))[s];
        uint4 u1 = ((const uint4*)(H + (size_t)c1.x * 64))[s];
        acc[0] += w0 * bf_lo(u0.x); acc[1] += w0 * bf_hi(u0.x);
        acc[2] += w0 * bf_lo(u0.y); acc[3] += w0 * bf_hi(u0.y);
        acc[4] += w0 * bf_lo(u0.z); acc[5] += w0 * bf_hi(u0.z);
        acc[6] += w0 * bf_lo(u0.w); acc[7] += w0 * bf_hi(u0.w);
        acc[0] += w1 * bf_lo(u1.x); acc[1] += w1 * bf_hi(u1.x);
        acc[2] += w1 * bf_lo(u1.y); acc[3] += w1 * bf_hi(u1.y);
        acc[4] += w1 * bf_lo(u1.z); acc[5] += w1 * bf_hi(u1.z);
        acc[6] += w1 * bf_lo(u1.w); acc[7] += w1 * bf_hi(u1.w);
    }
    // combine quarters
#pragma unroll
    for (int k = 0; k < 8; k++) {
        acc[k] += __shfl_xor(acc[k], 16);
        acc[k] += __shfl_xor(acc[k], 32);
    }
    // lane (q,s) writes features s*8 + 2q, s*8 + 2q + 1  -> fully coalesced 512B
    float o0 = (q == 0) ? acc[0] : (q == 1) ? acc[2] : (q == 2) ? acc[4] : acc[6];
    float o1 = (q == 0) ? acc[1] : (q == 1) ? acc[3] : (q == 2) ? acc[5] : acc[7];
    float2 bb = ((const float2*)bias)[s * 4 + q];
    ((float2*)(Out + (size_t)n * DIM))[s * 4 + q] = make_float2(o0 + bb.x, o1 + bb.y);
}

// GraphNorm stats: one block per graph, 512 thr (4 row-parts x 128 features)
__global__ __launch_bounds__(512) void k_stats(const float* __restrict__ A, const int* __restrict__ gstart,
                                               const float* __restrict__ mscale,
                                               float* __restrict__ amean, float* __restrict__ rstd) {
    __shared__ float L1[4][DIM];
    __shared__ float L2[4][DIM];
    int g = blockIdx.x;
    int t = threadIdx.x;
    int f = t & 127;
    int p = t >> 7;
    int s0 = gstart[g], s1 = gstart[g + 1];
    float s = 0.f, s2 = 0.f;
    for (int n = s0 + p; n < s1; n += 4) {
        float v = A[(size_t)n * DIM + f];
        s += v;
        s2 += v * v;
    }
    L1[p][f] = s; L2[p][f] = s2;
    __syncthreads();
    if (p == 0) {
        s = L1[0][f] + L1[1][f] + L1[2][f] + L1[3][f];
        s2 = L2[0][f] + L2[1][f] + L2[2][f] + L2[3][f];
        int cnt = s1 - s0;
        float inv = (cnt > 0) ? 1.0f / (float)cnt : 0.f;
        float m = s * inv;
        float a = mscale[f];
        float var = s2 * inv - (2.f * a - a * a) * m * m;
        amean[g * DIM + f] = a * m;
        rstd[g * DIM + f] = rsqrtf(var + EPSV);
    }
}

// final-layer norm (no next GEMM)
__global__ void k_norm_final(const float* __restrict__ A, const int* __restrict__ batch,
                             const float* __restrict__ amean, const float* __restrict__ rstd,
                             const float* __restrict__ gw, const float* __restrict__ gb,
                             const float* __restrict__ res, float* __restrict__ xout) {
    int i = blockIdx.x * blockDim.x + threadIdx.x;  // over N*32 float4 groups
    if (i >= N_NODES * 32) return;
    int n = i >> 5, q = i & 31;
    int g = batch[n];
    float4 v = ((const float4*)A)[i];
    float4 am = ((const float4*)amean)[g * 32 + q];
    float4 rs = ((const float4*)rstd)[g * 32 + q];
    float4 w = ((const float4*)gw)[q];
    float4 b = ((const float4*)gb)[q];
    float4 r = ((const float4*)res)[i];
    float4 o;
    o.x = w.x * (v.x - am.x) * rs.x + b.x;
    o.y = w.y * (v.y - am.y) * rs.y + b.y;
    o.z = w.z * (v.z - am.z) * rs.z + b.z;
    o.w = w.w * (v.w - am.w) * rs.w + b.w;
    o.x = ((o.x > 0.f) ? o.x : expm1f(o.x)) + r.x;
    o.y = ((o.y > 0.f) ? o.y : expm1f(o.y)) + r.y;
    o.z = ((o.z > 0.f) ? o.z : expm1f(o.z)) + r.z;
    o.w = ((o.w > 0.f) ? o.w : expm1f(o.w)) + r.w;
    ((float4*)xout)[i] = o;
}

// fused global_add_pool + dense head: one block per graph, 512 thr
__global__ __launch_bounds__(512) void k_pool_head(const float* __restrict__ X, const int* __restrict__ gstart,
                                                   const float* __restrict__ w1, const float* __restrict__ b1,
                                                   const float* __restrict__ gamma, const float* __restrict__ beta,
                                                   const float* __restrict__ rmean, const float* __restrict__ rvar,
                                                   const float* __restrict__ w2, const float* __restrict__ b2,
                                                   float* __restrict__ zout) {
    __shared__ float L[4][DIM];
    __shared__ float sp[DIM];
    __shared__ float sz[DIM];
    int g = blockIdx.x, t = threadIdx.x;
    int f = t & 127;
    int p = t >> 7;
    int s0 = gstart[g], s1 = gstart[g + 1];
    float s = 0.f;
    for (int n = s0 + p; n < s1; n += 4) s += X[(size_t)n * DIM + f];
    L[p][f] = s;
    __syncthreads();
    if (p == 0) sp[f] = L[0][f] + L[1][f] + L[2][f] + L[3][f];
    __syncthreads();
    if (p == 0) {
        float acc = b1[f];
#pragma unroll 8
        for (int k = 0; k < DIM; k++) acc += sp[k] * w1[k * DIM + f];
        acc = gamma[f] * (acc - rmean[f]) * rsqrtf(rvar[f] + EPSV) + beta[f];
        sz[f] = fmaxf(acc, 0.f);
    }
    __syncthreads();
    if (t < NCLS) {
        float a2 = b2[t];
#pragma unroll 8
        for (int k = 0; k < DIM; k++) a2 += sz[k] * w2[k * NCLS + t];
        zout[g * NCLS + t] = a2;
    }
}

// ---------------- launch ----------------

extern "C" void kernel_launch(void* const* d_in, const int* in_sizes, int n_in,
                              void* d_out, int out_size, void* d_ws, size_t ws_size,
                              hipStream_t stream) {
    const float* x_in   = (const float*)d_in[0];
    const int*   ei     = (const int*)d_in[1];
    const int*   batch  = (const int*)d_in[2];
    const float* conv_w = (const float*)d_in[3];
    const float* conv_b = (const float*)d_in[4];
    const float* gn_w   = (const float*)d_in[5];
    const float* gn_b   = (const float*)d_in[6];
    const float* gn_ms  = (const float*)d_in[7];
    const float* w1     = (const float*)d_in[8];
    const float* b1     = (const float*)d_in[9];
    const float* bng    = (const float*)d_in[10];
    const float* bnb    = (const float*)d_in[11];
    const float* bnm    = (const float*)d_in[12];
    const float* bnv    = (const float*)d_in[13];
    const float* w2     = (const float*)d_in[14];
    const float* b2     = (const float*)d_in[15];

    float* out_x = (float*)d_out;
    float* out_z = out_x + (size_t)N_NODES * DIM;

    char* ws = (char*)d_ws;
    size_t off = 0;
    auto alloc = [&](size_t bytes) -> void* {
        void* p = ws + off;
        off += (bytes + 255) / 256 * 256;
        return p;
    };
    uint32_t* h      = (uint32_t*)alloc(sizeof(uint32_t) * (size_t)N_PAD * 64);   // bf16 H (padded)
    float* agg       = (float*)alloc(sizeof(float) * (size_t)N_NODES * DIM);
    int2*  csc       = (int2*)alloc(sizeof(int2) * (size_t)N_EDGES);              // merged (src, w)
    int2*  binned    = (int2*)alloc(sizeof(int2) * (size_t)N_EDGES);              // pass-1 bins (src, dst)
    uint32_t* wt     = (uint32_t*)alloc(sizeof(uint32_t) * NLAYERS * DIM * 64);   // bf16 W^T
    int*   deg       = (int*)alloc(sizeof(int) * N_NODES);
    float* dis       = (float*)alloc(sizeof(float) * N_NODES);
    int*   rowoff    = (int*)alloc(sizeof(int) * (N_NODES + 1));
    int*   bsum      = (int*)alloc(sizeof(int) * SCAN_NB);
    int*   boff      = (int*)alloc(sizeof(int) * SCAN_NB);
    int*   bcur      = (int*)alloc(sizeof(int) * NBUCKET);
    int*   gstart    = (int*)alloc(sizeof(int) * (NGRAPH + 1));
    float* amean     = (float*)alloc(sizeof(float) * NGRAPH * DIM);
    float* rstd      = (float*)alloc(sizeof(float) * NGRAPH * DIM);

    // ---- prepass ----
    k_init<<<(N_NODES + 255) / 256, 256, 0, stream>>>(deg);
    k_edge_deg<<<(N_EDGES + 255) / 256, 256, 0, stream>>>(ei, deg);
    k_node_meta<<<(N_NODES + 255) / 256, 256, 0, stream>>>(deg, dis, batch, gstart);
    k_scan_bsum<<<SCAN_NB, SCAN_B, 0, stream>>>(deg, bsum);
    k_scan_mid<<<1, 256, 0, stream>>>(bsum, boff);
    k_scan_final<<<SCAN_NB, SCAN_B, 0, stream>>>(deg, boff, rowoff);
    k_bucket_init<<<1, 256, 0, stream>>>(rowoff, bcur);
    k_bin_edges<<<P1_BLOCKS, 256, 0, stream>>>(ei, bcur, binned);
    k_scatter<<<NBUCKET, 256, 0, stream>>>(binned, dis, rowoff, csc);
    k_cast_w<<<(NLAYERS * DIM * 64 + 255) / 256, 256, 0, stream>>>(conv_w, wt);

    // ---- layers ----
    k_gemm0<<<N_PAD / 64, 256, 0, stream>>>(x_in, wt, h);
    const float* xcur = x_in;
    for (int l = 0; l < NLAYERS; l++) {
        k_aggregate<<<N_NODES / 4, 256, 0, stream>>>(h, csc, rowoff, dis, conv_b + (size_t)l * DIM, agg);
        k_stats<<<NGRAPH, 512, 0, stream>>>(agg, gstart, gn_ms + (size_t)l * DIM, amean, rstd);
        if (l < NLAYERS - 1) {
            k_norm_gemm<<<N_PAD / 64, 256, 0, stream>>>(agg, batch, amean, rstd, gn_w + (size_t)l * DIM,
                                                        gn_b + (size_t)l * DIM, xcur, out_x,
                                                        wt + (size_t)(l + 1) * DIM * 64, h);
        } else {
            k_norm_final<<<(N_NODES * 32 + 255) / 256, 256, 0, stream>>>(agg, batch, amean, rstd,
                                                                         gn_w + (size_t)l * DIM,
                                                                         gn_b + (size_t)l * DIM, xcur, out_x);
        }
        xcur = out_x;
    }

    // ---- pool + head ----
    k_pool_head<<<NGRAPH, 512, 0, stream>>>(out_x, gstart, w1, b1, bng, bnb, bnm, bnv, w2, b2, out_z);
}

// Round 7
// 806.642 us; speedup vs baseline: 1.8831x; 1.2568x over previous
//
#include <hip/hip_runtime.h>
#include <stdint.h>

#define N_NODES 100000
#define N_PAD   100032            // 1563 * 64, padded rows for MFMA GEMM
#define N_EDGES 1600000
#define DIM 128
#define NLAYERS 4
#define NGRAPH 128
#define NCLS 10
#define EPSV 1e-5f

#define BIN_SHIFT 9
#define NBUCKET ((N_NODES + 511) >> 9)              // 196
#define P1_EPB 4096
#define P1_BLOCKS ((N_EDGES + P1_EPB - 1) / P1_EPB) // 391

typedef __attribute__((ext_vector_type(8))) short short8_t;   // 8 bf16
typedef __attribute__((ext_vector_type(4))) float float4_t;   // 4 fp32 acc

// ---------------- bf16 helpers ----------------

__device__ __forceinline__ float bf_lo(uint32_t u) { return __uint_as_float(u << 16); }
__device__ __forceinline__ float bf_hi(uint32_t u) { return __uint_as_float(u & 0xffff0000u); }
__device__ __forceinline__ uint32_t f2bf_rne(float f) {
    uint32_t x = __float_as_uint(f);
    return (x + 0x7fffu + ((x >> 16) & 1u)) >> 16;
}
__device__ __forceinline__ uint32_t pack_bf2(float a, float b) {
    return f2bf_rne(a) | (f2bf_rne(b) << 16);
}
__device__ __forceinline__ float4 unpack4(uint2 u) {
    return make_float4(bf_lo(u.x), bf_hi(u.x), bf_lo(u.y), bf_hi(u.y));
}

// ---------------- prepass kernels ----------------

// graph boundaries from SORTED batch (no atomics); also zero bucket counters
__global__ void k_node_meta(const int* __restrict__ batch, int* __restrict__ gstart,
                            int* __restrict__ bcnt) {
    int i = blockIdx.x * blockDim.x + threadIdx.x;
    if (i < NBUCKET) bcnt[i] = 0;
    if (i >= N_NODES) return;
    int b = batch[i];
    if (i == 0) {
        for (int g = 0; g <= b; g++) gstart[g] = 0;
    } else {
        int bp = batch[i - 1];
        for (int g = bp + 1; g <= b; g++) gstart[g] = i;
    }
    if (i == N_NODES - 1) {
        for (int g = b + 1; g <= NGRAPH; g++) gstart[g] = N_NODES;
    }
}

// histogram edges by dst bucket
__global__ __launch_bounds__(256) void k_bhist(const int* __restrict__ ei, int* __restrict__ bcnt) {
    __shared__ int hist[NBUCKET];
    int t = threadIdx.x;
    for (int i = t; i < NBUCKET; i += 256) hist[i] = 0;
    __syncthreads();
    int e0 = blockIdx.x * P1_EPB;
    int e1 = e0 + P1_EPB; if (e1 > N_EDGES) e1 = N_EDGES;
    for (int e = e0 + t; e < e1; e += 256) atomicAdd(&hist[ei[N_EDGES + e] >> BIN_SHIFT], 1);
    __syncthreads();
    for (int i = t; i < NBUCKET; i += 256) if (hist[i]) atomicAdd(&bcnt[i], hist[i]);
}

// exclusive scan of bucket counts -> bucket_off[0..NBUCKET]; init bcur
__global__ __launch_bounds__(256) void k_bscan(const int* __restrict__ bcnt,
                                               int* __restrict__ bucket_off, int* __restrict__ bcur) {
    __shared__ int s[256];
    int t = threadIdx.x;
    int v = (t < NBUCKET) ? bcnt[t] : 0;
    s[t] = v; __syncthreads();
    for (int off = 1; off < 256; off <<= 1) {
        int a = (t >= off) ? s[t - off] : 0;
        __syncthreads();
        s[t] += a;
        __syncthreads();
    }
    if (t < NBUCKET) { bucket_off[t] = s[t] - v; bcur[t] = s[t] - v; }
    if (t == 0) bucket_off[NBUCKET] = s[255];
}

// pass 1: bin edges by dst bucket (append-sequential writes per bucket)
__global__ __launch_bounds__(256) void k_bin_edges(const int* __restrict__ ei,
                                                   int* __restrict__ bcur,
                                                   int2* __restrict__ binned) {
    __shared__ int hist[NBUCKET];
    __shared__ int base[NBUCKET];
    int t = threadIdx.x;
    int e0 = blockIdx.x * P1_EPB;
    int e1 = e0 + P1_EPB; if (e1 > N_EDGES) e1 = N_EDGES;
    for (int i = t; i < NBUCKET; i += 256) hist[i] = 0;
    __syncthreads();
    int myrank[P1_EPB / 256];
    int cnt = 0;
    for (int e = e0 + t; e < e1; e += 256) {
        int d = ei[N_EDGES + e];
        myrank[cnt++] = atomicAdd(&hist[d >> BIN_SHIFT], 1);
    }
    __syncthreads();
    for (int i = t; i < NBUCKET; i += 256) base[i] = atomicAdd(&bcur[i], hist[i]);
    __syncthreads();
    cnt = 0;
    for (int e = e0 + t; e < e1; e += 256) {
        int s = ei[e];
        int d = ei[N_EDGES + e];
        binned[base[d >> BIN_SHIFT] + myrank[cnt++]] = make_int2(s, d);
    }
}

// per-bucket: histogram dst -> local scan -> rowoff + dis (replaces global deg+scan)
__global__ __launch_bounds__(256) void k_bucket_build(const int2* __restrict__ binned,
                                                      const int* __restrict__ bucket_off,
                                                      int* __restrict__ rowoff,
                                                      float* __restrict__ dis) {
    __shared__ int cnt[512];
    __shared__ int sa[512];
    __shared__ int sb[512];
    int b = blockIdx.x;
    int t = threadIdx.x;
    int n0 = b << BIN_SHIFT;
    int j0 = bucket_off[b], j1 = bucket_off[b + 1];
    cnt[t] = 0; cnt[t + 256] = 0;
    __syncthreads();
    for (int j = j0 + t; j < j1; j += 256) atomicAdd(&cnt[binned[j].y & 511], 1);
    __syncthreads();
    sa[t] = cnt[t]; sa[t + 256] = cnt[t + 256];
    __syncthreads();
    int* A = sa; int* B = sb;
    for (int off = 1; off < 512; off <<= 1) {
        int i0 = t, i1 = t + 256;
        B[i0] = A[i0] + ((i0 >= off) ? A[i0 - off] : 0);
        B[i1] = A[i1] + ((i1 >= off) ? A[i1 - off] : 0);
        __syncthreads();
        int* tmp = A; A = B; B = tmp;
    }
    // A = inclusive scan
    for (int i = t; i < 512; i += 256) {
        int n = n0 + i;
        if (n < N_NODES) {
            rowoff[n] = j0 + A[i] - cnt[i];
            dis[n] = rsqrtf((float)(1 + cnt[i]));
        }
    }
    if (b == NBUCKET - 1 && t == 0) rowoff[N_NODES] = N_EDGES;
}

// pass 2: one block per bucket; scatter within the bucket's L2-resident window.
__global__ __launch_bounds__(256) void k_scatter(const int2* __restrict__ binned,
                                                 const float* __restrict__ dis,
                                                 const int* __restrict__ rowoff,
                                                 const int* __restrict__ bucket_off,
                                                 int2* __restrict__ csc) {
    __shared__ int lcur[512];
    int b = blockIdx.x;
    int t = threadIdx.x;
    lcur[t] = 0; lcur[t + 256] = 0;
    __syncthreads();
    int j0 = bucket_off[b], j1 = bucket_off[b + 1];
    for (int j = j0 + t; j < j1; j += 256) {
        int2 sd = binned[j];
        float w = dis[sd.x] * dis[sd.y];
        int rank = atomicAdd(&lcur[sd.y & 511], 1);
        csc[rowoff[sd.y] + rank] = make_int2(sd.x, __float_as_int(w));
    }
}

// cast conv_w (fp32, [L][K][N]) -> Wt (bf16, [L][N][K] packed as uint pairs along K)
__global__ void k_cast_w(const float* __restrict__ W, uint32_t* __restrict__ Wt) {
    int i = blockIdx.x * blockDim.x + threadIdx.x;    // over L*128*64
    if (i >= NLAYERS * DIM * 64) return;
    int l = i / (DIM * 64);
    int n = (i / 64) % DIM;
    int ku = i % 64;
    const float* Wl = W + (size_t)l * DIM * DIM;
    float w0 = Wl[(2 * ku) * DIM + n];
    float w1 = Wl[(2 * ku + 1) * DIM + n];
    Wt[i] = pack_bf2(w0, w1);
}

// ---------------- GEMM cores ----------------

// MFMA phase: A-tile in LDS (uint [64][68], bf16 pairs), B = Wt global, out H bf16.
__device__ __forceinline__ void gemm_phase(const uint32_t (*atile)[68], const uint32_t* __restrict__ Wt,
                                           float (*ctile)[132], uint32_t* __restrict__ H,
                                           int blk, int t) {
    int wid = t >> 6;
    int lane = t & 63;
    int quad = lane >> 4;
    int s15 = lane & 15;

    float4_t acc[8];
#pragma unroll
    for (int i = 0; i < 8; i++) acc[i] = (float4_t){0.f, 0.f, 0.f, 0.f};

#pragma unroll
    for (int kk = 0; kk < 4; kk++) {
        uint4 au = *(const uint4*)&atile[wid * 16 + s15][quad * 4 + kk * 16];
        short8_t a = __builtin_bit_cast(short8_t, au);
#pragma unroll
        for (int nt = 0; nt < 8; nt++) {
            uint4 bu = *(const uint4*)(Wt + (size_t)(nt * 16 + s15) * 64 + kk * 16 + quad * 4);
            short8_t b = __builtin_bit_cast(short8_t, bu);
            acc[nt] = __builtin_amdgcn_mfma_f32_16x16x32_bf16(a, b, acc[nt], 0, 0, 0);
        }
    }
    __syncthreads();       // A-tile dead; reuse LDS for C
#pragma unroll
    for (int nt = 0; nt < 8; nt++) {
#pragma unroll
        for (int r = 0; r < 4; r++) {
            ctile[wid * 16 + quad * 4 + r][nt * 16 + s15] = acc[nt][r];
        }
    }
    __syncthreads();
    uint32_t* Hb = H + (size_t)blk * 64 * 64;
#pragma unroll
    for (int i = 0; i < 16; i++) {
        int idx = t + 256 * i;            // over 4096 uints
        int row = idx >> 6, cu = idx & 63;
        float2 v = *(const float2*)&ctile[row][cu * 2];
        Hb[(size_t)row * 64 + cu] = pack_bf2(v.x, v.y);
    }
}

// layer-0 GEMM: cast x_in (fp32) to bf16 A-tile in LDS, then MFMA
__global__ __launch_bounds__(256) void k_gemm0(const float* __restrict__ X, const uint32_t* __restrict__ Wt,
                                               uint32_t* __restrict__ H) {
    __shared__ __align__(16) char smem[64 * 132 * 4];
    uint32_t (*atile)[68] = (uint32_t(*)[68])smem;
    float (*ctile)[132] = (float(*)[132])smem;
    int t = threadIdx.x;
    size_t row0 = (size_t)blockIdx.x * 64;
#pragma unroll
    for (int i = 0; i < 8; i++) {
        int idx = t + 256 * i;            // 2048 float4-groups
        int row = idx >> 5, q = idx & 31;
        size_t gr = row0 + row;
        uint2 p = make_uint2(0u, 0u);
        if (gr < N_NODES) {
            float4 v = ((const float4*)(X + gr * DIM))[q];
            p.x = pack_bf2(v.x, v.y);
            p.y = pack_bf2(v.z, v.w);
        }
        *(uint2*)&atile[row][q * 2] = p;
    }
    __syncthreads();
    gemm_phase(atile, Wt, ctile, H, blockIdx.x, t);
}

// fused GraphNorm+ELU+residual (layer l) + GEMM (layer l+1).
// A = agg in bf16; residual in fp32 (layer 0) or bf16 (layers 1,2); writes bf16 residual out.
template <bool RBF>
__global__ __launch_bounds__(256) void k_norm_gemm(const uint32_t* __restrict__ A, const int* __restrict__ batch,
                                                   const float* __restrict__ amean, const float* __restrict__ rstd,
                                                   const float* __restrict__ gw, const float* __restrict__ gb,
                                                   const void* __restrict__ res, uint32_t* __restrict__ res_out,
                                                   const uint32_t* __restrict__ Wt, uint32_t* __restrict__ H) {
    __shared__ __align__(16) char smem[64 * 132 * 4];
    uint32_t (*atile)[68] = (uint32_t(*)[68])smem;
    float (*ctile)[132] = (float(*)[132])smem;
    int t = threadIdx.x;
    size_t row0 = (size_t)blockIdx.x * 64;
#pragma unroll
    for (int i = 0; i < 8; i++) {
        int idx = t + 256 * i;            // 2048 float4-groups
        int row = idx >> 5, q = idx & 31;
        size_t gr = row0 + row;
        uint2 p = make_uint2(0u, 0u);
        if (gr < N_NODES) {
            int g = batch[gr];
            float4 v = unpack4(((const uint2*)(A + gr * 64))[q]);
            float4 am = ((const float4*)amean)[g * 32 + q];
            float4 rs = ((const float4*)rstd)[g * 32 + q];
            float4 w = ((const float4*)gw)[q];
            float4 b = ((const float4*)gb)[q];
            float4 r;
            if (RBF) r = unpack4(((const uint2*)((const uint32_t*)res + gr * 64))[q]);
            else     r = ((const float4*)res)[gr * 32 + q];
            float4 o;
            o.x = w.x * (v.x - am.x) * rs.x + b.x;
            o.y = w.y * (v.y - am.y) * rs.y + b.y;
            o.z = w.z * (v.z - am.z) * rs.z + b.z;
            o.w = w.w * (v.w - am.w) * rs.w + b.w;
            o.x = ((o.x > 0.f) ? o.x : expm1f(o.x)) + r.x;
            o.y = ((o.y > 0.f) ? o.y : expm1f(o.y)) + r.y;
            o.z = ((o.z > 0.f) ? o.z : expm1f(o.z)) + r.z;
            o.w = ((o.w > 0.f) ? o.w : expm1f(o.w)) + r.w;
            p.x = pack_bf2(o.x, o.y);
            p.y = pack_bf2(o.z, o.w);
            ((uint2*)(res_out + gr * 64))[q] = p;
        }
        *(uint2*)&atile[row][q * 2] = p;
    }
    __syncthreads();
    gemm_phase(atile, Wt, ctile, H, blockIdx.x, t);
}

// ---------------- per-layer kernels ----------------

// pull aggregation: 1 wave per node, quarter-wave rows; writes bf16-packed agg.
__global__ __launch_bounds__(256) void k_aggregate(const uint32_t* __restrict__ H,
                                                   const int2* __restrict__ csc,
                                                   const int* __restrict__ rowoff,
                                                   const float* __restrict__ dis,
                                                   const float* __restrict__ bias,
                                                   uint32_t* __restrict__ Out) {
    int wid = threadIdx.x >> 6;
    int lane = threadIdx.x & 63;
    int q = lane >> 4;
    int s = lane & 15;
    int n = blockIdx.x * 4 + wid;     // grid = N/4 exactly

    float acc[8];
    {
        float d = dis[n];
        float sw = (q == 0) ? d * d : 0.f;     // self term counted once (quad 0)
        uint4 us = ((const uint4*)(H + (size_t)n * 64))[s];
        acc[0] = sw * bf_lo(us.x); acc[1] = sw * bf_hi(us.x);
        acc[2] = sw * bf_lo(us.y); acc[3] = sw * bf_hi(us.y);
        acc[4] = sw * bf_lo(us.z); acc[5] = sw * bf_hi(us.z);
        acc[6] = sw * bf_lo(us.w); acc[7] = sw * bf_hi(us.w);
    }

    int b0 = rowoff[n], b1 = rowoff[n + 1];
    for (int j = b0; j < b1; j += 8) {
        int e0 = j + q;
        int e1 = j + 4 + q;
        int2 c0 = csc[(e0 < b1) ? e0 : b0];
        int2 c1 = csc[(e1 < b1) ? e1 : b0];
        float w0 = (e0 < b1) ? __int_as_float(c0.y) : 0.f;
        float w1 = (e1 < b1) ? __int_as_float(c1.y) : 0.f;
        uint4 u0 = ((const uint4*)(H + (size_t)c0.x * 64))[s];
        uint4 u1 = ((const uint4*)(H + (size_t)c1.x * 64))[s];
        acc[0] += w0 * bf_lo(u0.x); acc[1] += w0 * bf_hi(u0.x);
        acc[2] += w0 * bf_lo(u0.y); acc[3] += w0 * bf_hi(u0.y);
        acc[4] += w0 * bf_lo(u0.z); acc[5] += w0 * bf_hi(u0.z);
        acc[6] += w0 * bf_lo(u0.w); acc[7] += w0 * bf_hi(u0.w);
        acc[0] += w1 * bf_lo(u1.x); acc[1] += w1 * bf_hi(u1.x);
        acc[2] += w1 * bf_lo(u1.y); acc[3] += w1 * bf_hi(u1.y);
        acc[4] += w1 * bf_lo(u1.z); acc[5] += w1 * bf_hi(u1.z);
        acc[6] += w1 * bf_lo(u1.w); acc[7] += w1 * bf_hi(u1.w);
    }
    // combine quarters
#pragma unroll
    for (int k = 0; k < 8; k++) {
        acc[k] += __shfl_xor(acc[k], 16);
        acc[k] += __shfl_xor(acc[k], 32);
    }
    // lane (q,s) owns feature pair index s*4+q (feats s*8+2q, s*8+2q+1) -> coalesced 256B
    float o0 = (q == 0) ? acc[0] : (q == 1) ? acc[2] : (q == 2) ? acc[4] : acc[6];
    float o1 = (q == 0) ? acc[1] : (q == 1) ? acc[3] : (q == 2) ? acc[5] : acc[7];
    float2 bb = ((const float2*)bias)[s * 4 + q];
    Out[(size_t)n * 64 + s * 4 + q] = pack_bf2(o0 + bb.x, o1 + bb.y);
}

// GraphNorm stats from bf16 agg: one block per graph, 512 thr (8 parts x 64 uints)
__global__ __launch_bounds__(512) void k_stats(const uint32_t* __restrict__ A, const int* __restrict__ gstart,
                                               const float* __restrict__ mscale,
                                               float* __restrict__ amean, float* __restrict__ rstd) {
    __shared__ float L1[8][DIM];
    __shared__ float L2[8][DIM];
    int g = blockIdx.x;
    int t = threadIdx.x;
    int f2 = t & 63;
    int p = t >> 6;
    int s0 = gstart[g], s1 = gstart[g + 1];
    float sa = 0.f, sb = 0.f, qa = 0.f, qb = 0.f;
    for (int n = s0 + p; n < s1; n += 8) {
        uint32_t u = A[(size_t)n * 64 + f2];
        float a = bf_lo(u), b = bf_hi(u);
        sa += a; qa += a * a;
        sb += b; qb += b * b;
    }
    L1[p][2 * f2] = sa; L1[p][2 * f2 + 1] = sb;
    L2[p][2 * f2] = qa; L2[p][2 * f2 + 1] = qb;
    __syncthreads();
    if (t < DIM) {
        float s = 0.f, s2 = 0.f;
#pragma unroll
        for (int i = 0; i < 8; i++) { s += L1[i][t]; s2 += L2[i][t]; }
        int cnt = s1 - s0;
        float inv = (cnt > 0) ? 1.0f / (float)cnt : 0.f;
        float m = s * inv;
        float a = mscale[t];
        float var = s2 * inv - (2.f * a - a * a) * m * m;
        amean[g * DIM + t] = a * m;
        rstd[g * DIM + t] = rsqrtf(var + EPSV);
    }
}

// fused final-layer norm+ELU+residual + x write + global_add_pool + dense head
__global__ __launch_bounds__(512) void k_pool_head(const uint32_t* __restrict__ A,
                                                   const uint32_t* __restrict__ resb,
                                                   const int* __restrict__ gstart,
                                                   const float* __restrict__ amean, const float* __restrict__ rstd,
                                                   const float* __restrict__ gw, const float* __restrict__ gb,
                                                   const float* __restrict__ w1, const float* __restrict__ b1,
                                                   const float* __restrict__ gamma, const float* __restrict__ beta,
                                                   const float* __restrict__ rmean, const float* __restrict__ rvar,
                                                   const float* __restrict__ w2, const float* __restrict__ b2,
                                                   float* __restrict__ outx, float* __restrict__ zout) {
    __shared__ float L[8][DIM];
    __shared__ float sp[DIM];
    __shared__ float sz[DIM];
    int g = blockIdx.x, t = threadIdx.x;
    int f2 = t & 63;
    int p = t >> 6;
    int s0 = gstart[g], s1 = gstart[g + 1];
    float am0 = amean[g * DIM + 2 * f2], am1 = amean[g * DIM + 2 * f2 + 1];
    float rs0 = rstd[g * DIM + 2 * f2],  rs1 = rstd[g * DIM + 2 * f2 + 1];
    float w0_ = gw[2 * f2], w1_ = gw[2 * f2 + 1];
    float b0_ = gb[2 * f2], b1_ = gb[2 * f2 + 1];
    float p0 = 0.f, p1 = 0.f;
    for (int n = s0 + p; n < s1; n += 8) {
        uint32_t u = A[(size_t)n * 64 + f2];
        uint32_t ur = resb[(size_t)n * 64 + f2];
        float a = bf_lo(u), b = bf_hi(u);
        float r0 = bf_lo(ur), r1 = bf_hi(ur);
        float o0 = w0_ * (a - am0) * rs0 + b0_;
        float o1 = w1_ * (b - am1) * rs1 + b1_;
        o0 = ((o0 > 0.f) ? o0 : expm1f(o0)) + r0;
        o1 = ((o1 > 0.f) ? o1 : expm1f(o1)) + r1;
        ((float2*)(outx + (size_t)n * DIM))[f2] = make_float2(o0, o1);
        p0 += o0; p1 += o1;
    }
    L[p][2 * f2] = p0; L[p][2 * f2 + 1] = p1;
    __syncthreads();
    if (t < DIM) {
        float s = 0.f;
#pragma unroll
        for (int i = 0; i < 8; i++) s += L[i][t];
        sp[t] = s;
    }
    __syncthreads();
    if (t < DIM) {
        float acc = b1[t];
#pragma unroll 8
        for (int k = 0; k < DIM; k++) acc += sp[k] * w1[k * DIM + t];
        acc = gamma[t] * (acc - rmean[t]) * rsqrtf(rvar[t] + EPSV) + beta[t];
        sz[t] = fmaxf(acc, 0.f);
    }
    __syncthreads();
    if (t < NCLS) {
        float a2 = b2[t];
#pragma unroll 8
        for (int k = 0; k < DIM; k++) a2 += sz[k] * w2[k * NCLS + t];
        zout[g * NCLS + t] = a2;
    }
}

// ---------------- launch ----------------

extern "C" void kernel_launch(void* const* d_in, const int* in_sizes, int n_in,
                              void* d_out, int out_size, void* d_ws, size_t ws_size,
                              hipStream_t stream) {
    const float* x_in   = (const float*)d_in[0];
    const int*   ei     = (const int*)d_in[1];
    const int*   batch  = (const int*)d_in[2];
    const float* conv_w = (const float*)d_in[3];
    const float* conv_b = (const float*)d_in[4];
    const float* gn_w   = (const float*)d_in[5];
    const float* gn_b   = (const float*)d_in[6];
    const float* gn_ms  = (const float*)d_in[7];
    const float* w1     = (const float*)d_in[8];
    const float* b1     = (const float*)d_in[9];
    const float* bng    = (const float*)d_in[10];
    const float* bnb    = (const float*)d_in[11];
    const float* bnm    = (const float*)d_in[12];
    const float* bnv    = (const float*)d_in[13];
    const float* w2     = (const float*)d_in[14];
    const float* b2     = (const float*)d_in[15];

    float* out_x = (float*)d_out;
    float* out_z = out_x + (size_t)N_NODES * DIM;

    char* ws = (char*)d_ws;
    size_t off = 0;
    auto alloc = [&](size_t bytes) -> void* {
        void* p = ws + off;
        off += (bytes + 255) / 256 * 256;
        return p;
    };
    uint32_t* h      = (uint32_t*)alloc(sizeof(uint32_t) * (size_t)N_PAD * 64);   // bf16 H (padded)
    uint32_t* agg    = (uint32_t*)alloc(sizeof(uint32_t) * (size_t)N_NODES * 64); // bf16 agg
    uint32_t* resb   = (uint32_t*)alloc(sizeof(uint32_t) * (size_t)N_NODES * 64); // bf16 residual stream
    int2*  csc       = (int2*)alloc(sizeof(int2) * (size_t)N_EDGES);              // merged (src, w)
    int2*  binned    = (int2*)alloc(sizeof(int2) * (size_t)N_EDGES);              // pass-1 bins (src, dst)
    uint32_t* wt     = (uint32_t*)alloc(sizeof(uint32_t) * NLAYERS * DIM * 64);   // bf16 W^T
    float* dis       = (float*)alloc(sizeof(float) * N_NODES);
    int*   rowoff    = (int*)alloc(sizeof(int) * (N_NODES + 1));
    int*   bcnt      = (int*)alloc(sizeof(int) * NBUCKET);
    int*   boffb     = (int*)alloc(sizeof(int) * (NBUCKET + 1));
    int*   bcur      = (int*)alloc(sizeof(int) * NBUCKET);
    int*   gstart    = (int*)alloc(sizeof(int) * (NGRAPH + 1));
    float* amean     = (float*)alloc(sizeof(float) * NGRAPH * DIM);
    float* rstd      = (float*)alloc(sizeof(float) * NGRAPH * DIM);

    // ---- prepass ----
    k_node_meta<<<(N_NODES + 255) / 256, 256, 0, stream>>>(batch, gstart, bcnt);
    k_bhist<<<P1_BLOCKS, 256, 0, stream>>>(ei, bcnt);
    k_bscan<<<1, 256, 0, stream>>>(bcnt, boffb, bcur);
    k_bin_edges<<<P1_BLOCKS, 256, 0, stream>>>(ei, bcur, binned);
    k_bucket_build<<<NBUCKET, 256, 0, stream>>>(binned, boffb, rowoff, dis);
    k_scatter<<<NBUCKET, 256, 0, stream>>>(binned, dis, rowoff, boffb, csc);
    k_cast_w<<<(NLAYERS * DIM * 64 + 255) / 256, 256, 0, stream>>>(conv_w, wt);

    // ---- layers ----
    k_gemm0<<<N_PAD / 64, 256, 0, stream>>>(x_in, wt, h);
    for (int l = 0; l < NLAYERS; l++) {
        k_aggregate<<<N_NODES / 4, 256, 0, stream>>>(h, csc, rowoff, dis, conv_b + (size_t)l * DIM, agg);
        k_stats<<<NGRAPH, 512, 0, stream>>>(agg, gstart, gn_ms + (size_t)l * DIM, amean, rstd);
        if (l == 0) {
            k_norm_gemm<false><<<N_PAD / 64, 256, 0, stream>>>(agg, batch, amean, rstd, gn_w, gn_b,
                                                               (const void*)x_in, resb,
                                                               wt + (size_t)1 * DIM * 64, h);
        } else if (l < NLAYERS - 1) {
            k_norm_gemm<true><<<N_PAD / 64, 256, 0, stream>>>(agg, batch, amean, rstd,
                                                              gn_w + (size_t)l * DIM, gn_b + (size_t)l * DIM,
                                                              (const void*)resb, resb,
                                                              wt + (size_t)(l + 1) * DIM * 64, h);
        } else {
            k_pool_head<<<NGRAPH, 512, 0, stream>>>(agg, resb, gstart, amean, rstd,
                                                    gn_w + (size_t)l * DIM, gn_b + (size_t)l * DIM,
                                                    w1, b1, bng, bnb, bnm, bnv, w2, b2, out_x, out_z);
        }
    }
}